// Round 9
// baseline (1774.916 us; speedup 1.0000x reference)
//
#include <hip/hip_runtime.h>
#include <hip/hip_bf16.h>

typedef unsigned short ushort_t;
typedef __attribute__((ext_vector_type(8))) short short8v;
typedef __attribute__((ext_vector_type(4))) float f32x4;

__device__ __forceinline__ ushort_t f2bs(float v) {
  union { __hip_bfloat16 h; ushort_t u; } cv;
  cv.h = __float2bfloat16(v);
  return cv.u;
}
__device__ __forceinline__ float bs2f(ushort_t u) {
  union { ushort_t u; __hip_bfloat16 h; } cv;
  cv.u = u;
  return __bfloat162float(cv.h);
}

// ---------------- workspace layout (unchanged from r8) ----------------
static constexpr size_t OFF_P = 0;
static constexpr size_t OFF_ENORM = 4194304;
static constexpr size_t OFF_WTD2 = 4194816;
static constexpr size_t OFF_ACC = 4207360;
static constexpr size_t OFF_ZROW = 4207368;
static constexpr size_t OFF_SHORT = 4207432;
static constexpr size_t SO_H1H = 0;
static constexpr size_t SO_H1L = 16777216;
static constexpr size_t SO_NBH = 33554432;
static constexpr size_t SO_NBL = 37748736;
static constexpr size_t SO_W1H = 41943040;
static constexpr size_t SO_W1L = 41959424;
static constexpr size_t SO_W2H = 41975808;
static constexpr size_t SO_W2L = 43024384;
static constexpr size_t SO_W3EH = 44072960;
static constexpr size_t SO_W3EL = 45252608;
static constexpr size_t SO_W3D = 46432256;
static constexpr size_t SO_W1REH = 47611904;
static constexpr size_t SO_W1REL = 47742976;
static constexpr size_t SO_W1RD = 47874048;
static constexpr size_t SO_WD1 = 48005120;

__device__ __forceinline__ void split_store(float v, ushort_t* hi, ushort_t* lo, size_t i) {
  ushort_t h = f2bs(v);
  hi[i] = h;
  lo[i] = f2bs(v - bs2f(h));
}

// ---------------- fused prep ----------------
__global__ void __launch_bounds__(256) k_prep(
    const float* __restrict__ x, const float* __restrict__ ew1,
    const float* __restrict__ ew2, const float* __restrict__ r3w,
    const float* __restrict__ r1w, const float* __restrict__ dw1,
    const float* __restrict__ dw2, const float* __restrict__ emb,
    ushort_t* __restrict__ W1H, ushort_t* __restrict__ W1L,
    ushort_t* __restrict__ W2H, ushort_t* __restrict__ W2L,
    ushort_t* __restrict__ W3EH, ushort_t* __restrict__ W3EL,
    ushort_t* __restrict__ W3D, ushort_t* __restrict__ W1REH,
    ushort_t* __restrict__ W1REL, ushort_t* __restrict__ W1RD,
    ushort_t* __restrict__ WD1, float* __restrict__ wTd2,
    float* __restrict__ enorm, float* __restrict__ acc, float* __restrict__ zrow,
    ushort_t* __restrict__ A1H, ushort_t* __restrict__ A1L) {
  int b = blockIdx.x, t = threadIdx.x;
  if (b < 64) {
    int i = b * 256 + t;
    int oc = i >> 6, k = i & 63;
    float v = 0.f;
    if (k < 48) {
      int tap = k / 3, ic = k - 3 * tap;
      v = ew1[(oc * 3 + ic) * 16 + tap];
    }
    split_store(v, W1H, W1L, i);
  } else if (b < 4160) {
    int i = (b - 64) * 256 + t;
    int oc = i >> 12, k = i & 4095;
    int tap = k >> 8, ic = k & 255;
    split_store(ew2[(oc * 256 + ic) * 16 + tap], W2H, W2L, i);
  } else if (b < 8768) {
    int i = (b - 4160) * 256 + t;
    int rb = i / 589824, r2 = i - rb * 589824;
    int oc = r2 / 2304, k = r2 - oc * 2304;
    int r9 = k >> 8, ic = k & 255;
    split_store(r3w[((rb * 256 + oc) * 256 + ic) * 9 + r9], W3EH, W3EL, i);
  } else if (b < 13376) {
    int i = (b - 8768) * 256 + t;
    int rb = i / 589824, r2 = i - rb * 589824;
    int oc = r2 / 2304, k = r2 - oc * 2304;
    int r9 = k >> 8, ic = k & 255;
    W3D[i] = f2bs(r3w[(((rb + 2) * 256 + oc) * 256 + ic) * 9 + r9]);
  } else if (b < 13888) {
    int i = (b - 13376) * 256 + t;
    split_store(r1w[i], W1REH, W1REL, i);
  } else if (b < 14400) {
    int i = (b - 13888) * 256 + t;
    W1RD[i] = f2bs(r1w[2 * 65536 + i]);
  } else if (b < 18496) {
    int i = (b - 14400) * 256 + t;
    int cls = i >> 18, r2 = i & 262143;
    int oc = r2 >> 10, k = r2 & 1023;
    int tap = k >> 8, ic = k & 255;
    int s = tap >> 1, sx = tap & 1;
    int py = cls >> 1, px = cls & 1;
    int ky = py + 2 - 2 * s, kx = px + 2 - 2 * sx;
    WD1[i] = f2bs(dw1[(ic * 256 + oc) * 16 + ky * 4 + kx]);
  } else if (b < 18544) {
    int i = (b - 18496) * 256 + t;
    if (i < 12288) {
      int kyx = i & 15;
      int r = i >> 4;
      int oc = r % 3;
      int ic = r / 3;
      wTd2[(ic * 16 + kyx) * 3 + oc] = dw2[i];
    }
  } else if (b < 18546) {
    int e = (b - 18544) * 256 + t;
    float s = 0.f;
    for (int c = 0; c < 256; ++c) {
      float v = emb[e * 256 + c];
      s += v * v;
    }
    enorm[e] = s;
  } else if (b == 18546) {
    if (t < 2) acc[t] = 0.f;
    if (t < 64) zrow[t] = 0.f;
  } else {
    int i = (b - 18547) * 256 + t;
    int t1 = i >> 6, k = i & 63;
    float v = 0.f;
    if (k < 48) {
      int tap = k / 3, ic = k - 3 * tap;
      int n = t1 >> 8, oy = (t1 >> 4) & 15, ox = t1 & 15;
      int ky = tap >> 2, kx = tap & 3;
      int iy = 2 * oy - 1 + ky, ix = 2 * ox - 1 + kx;
      if ((unsigned)iy < 32u && (unsigned)ix < 32u)
        v = x[((n * 3 + ic) * 32 + iy) * 32 + ix];
    }
    split_store(v, A1H, A1L, i);
  }
}

// ---------------- register-direct MFMA GEMM (no LDS, no barriers) ----------------
// Block = BM64 x BN128, 4 waves as 2x2; wave tile 32x64 (2 m-frags x 4 n-frags).
// Fragments loaded straight global->VGPR per lane (A[m=l&15][k=quad*8+j]); the
// K-loop has NO __syncthreads, so next-window loads overlap current MFMAs.
// STYLE 1 (split, BK=32): AhBh + AlBh + AhBl per (mi,nj). STYLE 0 (BK=64): 2 chunks.
// MODE: 0=direct A (stride KK), 1=conv2 im2col (16x16 grid), 2=res3 3x3 (8x8),
//       3=deconv1 tap (8x8, cls=blockIdx.z)
// EPI: 1=relu->f32, 2=res+relu->f32, 3=deconv1 remap relu->bf16,
//      4=relu->split bf16, 5=res+relu->f32+bf16 copy
template <int KK, int MODE, int EPI, int STYLE>
__global__ __launch_bounds__(256, 1) void k_gemm(
    const ushort_t* __restrict__ Ah, const ushort_t* __restrict__ Al,
    const ushort_t* __restrict__ Bh, const ushort_t* __restrict__ Bl,
    const float* __restrict__ bias, const float* __restrict__ res,
    float* __restrict__ outf, ushort_t* __restrict__ outb,
    ushort_t* __restrict__ outb2, const ushort_t* __restrict__ zrow) {
  const int t = threadIdx.x;
  const int w = t >> 6, l = t & 63;
  const int wm = w & 1, wn = w >> 1;
  const int fr = l & 15, quad = l >> 4;
  const int M0 = blockIdx.x * 64, N0 = blockIdx.y * 128;
  int py = 0, px = 0;
  const ushort_t* Bb = Bh;
  if (MODE == 3) {
    int cls = blockIdx.z;
    py = cls >> 1;
    px = cls & 1;
    Bb = Bh + (size_t)cls * 262144;
  }
  int tok[2], rn[2], roy[2], rox[2];
  size_t abase[2];
#pragma unroll
  for (int mi = 0; mi < 2; ++mi) {
    tok[mi] = M0 + wm * 32 + mi * 16 + fr;
    rn[mi] = tok[mi] >> 6;
    roy[mi] = (tok[mi] >> 3) & 7;
    rox[mi] = tok[mi] & 7;
    abase[mi] = (size_t)tok[mi] * KK + quad * 8;
  }
  size_t bbase[4];
#pragma unroll
  for (int nj = 0; nj < 4; ++nj)
    bbase[nj] = (size_t)(N0 + wn * 64 + nj * 16 + fr) * KK + quad * 8;
  const ushort_t* zp = zrow + quad * 8;

  f32x4 acc[2][4];
#pragma unroll
  for (int i = 0; i < 2; ++i)
#pragma unroll
    for (int j = 0; j < 4; ++j) acc[i][j] = (f32x4){0.f, 0.f, 0.f, 0.f};

  const int STEP = (STYLE == 1) ? 32 : 64;
  for (int kk = 0; kk < KK; kk += STEP) {
    short8v rA0[2], rA1[2], rB0[4], rB1[4];
#pragma unroll
    for (int mi = 0; mi < 2; ++mi) {
      const ushort_t *pa0, *pa1;
      if (MODE == 0) {
        size_t o = abase[mi] + kk;
        pa0 = Ah + o;
        pa1 = (STYLE == 1) ? Al + o : Ah + o + 32;
      } else {
        int tap = kk >> 8, kin = (kk & 255) + quad * 8;
        int iy, ix;
        unsigned lim;
        if (MODE == 1) {
          int ky = tap >> 2, kx = tap & 3;
          iy = 2 * roy[mi] - 1 + ky;
          ix = 2 * rox[mi] - 1 + kx;
          lim = 16u;
        } else if (MODE == 2) {
          int ky = tap / 3, kx = tap - ky * 3;
          iy = roy[mi] - 1 + ky;
          ix = rox[mi] - 1 + kx;
          lim = 8u;
        } else {
          int s = tap >> 1, sx = tap & 1;
          iy = roy[mi] + s - py;
          ix = rox[mi] + sx - px;
          lim = 8u;
        }
        bool v = ((unsigned)iy < lim && (unsigned)ix < lim);
        size_t r = (MODE == 1) ? ((size_t)((rn[mi] << 8) + (iy << 4) + ix) << 8)
                               : ((size_t)((rn[mi] << 6) + (iy << 3) + ix) << 8);
        size_t o = r + kin;
        pa0 = v ? Ah + o : zp;
        pa1 = (STYLE == 1) ? (v ? Al + o : zp) : (v ? Ah + o + 32 : zp);
      }
      rA0[mi] = *(const short8v*)pa0;
      rA1[mi] = *(const short8v*)pa1;
    }
#pragma unroll
    for (int nj = 0; nj < 4; ++nj) {
      size_t o = bbase[nj] + kk;
      rB0[nj] = *(const short8v*)(Bb + o);
      rB1[nj] = (STYLE == 1) ? *(const short8v*)(Bl + o) : *(const short8v*)(Bb + o + 32);
    }
#pragma unroll
    for (int mi = 0; mi < 2; ++mi)
#pragma unroll
      for (int nj = 0; nj < 4; ++nj) {
        acc[mi][nj] =
            __builtin_amdgcn_mfma_f32_16x16x32_bf16(rA0[mi], rB0[nj], acc[mi][nj], 0, 0, 0);
        if (STYLE == 1) {
          acc[mi][nj] =
              __builtin_amdgcn_mfma_f32_16x16x32_bf16(rA1[mi], rB0[nj], acc[mi][nj], 0, 0, 0);
          acc[mi][nj] =
              __builtin_amdgcn_mfma_f32_16x16x32_bf16(rA0[mi], rB1[nj], acc[mi][nj], 0, 0, 0);
        } else {
          acc[mi][nj] =
              __builtin_amdgcn_mfma_f32_16x16x32_bf16(rA1[mi], rB1[nj], acc[mi][nj], 0, 0, 0);
        }
      }
  }

#pragma unroll
  for (int mi = 0; mi < 2; ++mi) {
#pragma unroll
    for (int nj = 0; nj < 4; ++nj) {
      int col = N0 + wn * 64 + nj * 16 + fr;
      float bv = bias[col];
#pragma unroll
      for (int i = 0; i < 4; ++i) {
        int m = M0 + wm * 32 + mi * 16 + quad * 4 + i;
        float v = fmaxf(acc[mi][nj][i] + bv, 0.f);
        if (EPI == 1) {
          outf[(size_t)m * 256 + col] = v;
        } else if (EPI == 2) {
          size_t o = (size_t)m * 256 + col;
          outf[o] = res[o] + v;
        } else if (EPI == 3) {
          int nn = m >> 6, jj = (m >> 3) & 7, ii = m & 7;
          int oy = 2 * jj + 1 - py, ox = 2 * ii + 1 - px;
          outb[(size_t)((nn << 8) + oy * 16 + ox) * 256 + col] = f2bs(v);
        } else if (EPI == 4) {
          size_t o = (size_t)m * 256 + col;
          ushort_t h = f2bs(v);
          outb[o] = h;
          outb2[o] = f2bs(v - bs2f(h));
        } else {  // EPI 5
          size_t o = (size_t)m * 256 + col;
          float vv = res[o] + v;
          outf[o] = vv;
          outb[o] = f2bs(vv);
        }
      }
    }
  }
}

// ---------------- fused rmsnorm (coalesced rmsw via transposed LDS stage) ----------
// rmsw slice layout [c=256][yx=64]; staged into LDS as [yx][257] (pad kills conflicts)
template <int SPLIT>
__global__ void __launch_bounds__(256) k_rmsnorm(const float* __restrict__ in,
                                                 const float* __restrict__ rmsw,
                                                 ushort_t* __restrict__ NBh,
                                                 ushort_t* __restrict__ NBl) {
  extern __shared__ float wT[];  // 64*257 floats
  __shared__ float sd[256];
  __shared__ float s_scale;
  int n = blockIdx.x, t = threadIdx.x;
  const float* p = in + (size_t)n * 16384;
  for (int k = 0; k < 64; ++k) {
    int i = k * 256 + t;  // i = c*64 + j
    wT[(i & 63) * 257 + (i >> 6)] = rmsw[i];
  }
  float s = 0.f;
  const float4* p4 = (const float4*)p;
  for (int i = t; i < 4096; i += 256) {
    float4 v = p4[i];
    s += v.x * v.x + v.y * v.y + v.z * v.z + v.w * v.w;
  }
  sd[t] = s;
  __syncthreads();
  for (int k = 128; k > 0; k >>= 1) {
    if (t < k) sd[t] += sd[t + k];
    __syncthreads();
  }
  if (t == 0) s_scale = 1.0f / sqrtf(sd[0] / 16384.f + 1.1920929e-07f);
  __syncthreads();
  float scale = s_scale;
  ushort_t* oh = NBh + (size_t)n * 16384;
  ushort_t* ol = NBl + (size_t)n * 16384;
  for (int j = 0; j < 64; ++j) {
    int i = j * 256 + t;
    float v = p[i] * scale * wT[j * 257 + t];
    ushort_t h = f2bs(v);
    oh[i] = h;
    if (SPLIT) ol[i] = f2bs(v - bs2f(h));
  }
}

// ---------------- VQ ----------------
__global__ void __launch_bounds__(256) k_vq(const float* __restrict__ enc,
                                            const float* __restrict__ emb,
                                            const float* __restrict__ enorm,
                                            float* __restrict__ q, float* __restrict__ sse) {
  __shared__ float z[16][256];
  __shared__ float sc[512 * 16];
  __shared__ float bv[16][16];
  __shared__ int bi[16][16];
  __shared__ int idxs[16];
  int T0 = blockIdx.x * 16;
  int t = threadIdx.x;
  for (int j = 0; j < 16; ++j) z[j][t] = enc[(size_t)(T0 + j) * 256 + t];
  __syncthreads();
  float d0[16], d1[16];
#pragma unroll
  for (int j = 0; j < 16; ++j) { d0[j] = 0.f; d1[j] = 0.f; }
  const float4* e0 = (const float4*)(emb + (size_t)t * 256);
  const float4* e1 = (const float4*)(emb + (size_t)(t + 256) * 256);
  for (int c4 = 0; c4 < 64; ++c4) {
    float4 ea = e0[c4];
    float4 eb = e1[c4];
#pragma unroll
    for (int j = 0; j < 16; ++j) {
      float4 zv = *(const float4*)&z[j][c4 * 4];
      d0[j] += zv.x * ea.x + zv.y * ea.y + zv.z * ea.z + zv.w * ea.w;
      d1[j] += zv.x * eb.x + zv.y * eb.y + zv.z * eb.z + zv.w * eb.w;
    }
  }
  float en0 = enorm[t], en1 = enorm[t + 256];
#pragma unroll
  for (int j = 0; j < 16; ++j) {
    sc[t * 16 + j] = en0 - 2.f * d0[j];
    sc[(t + 256) * 16 + j] = en1 - 2.f * d1[j];
  }
  __syncthreads();
  {
    int j = t & 15, chunk = t >> 4;
    float best = 3.4e38f;
    int bidx = 0;
    int c0 = chunk * 32;
    for (int cc = 0; cc < 32; ++cc) {
      float v = sc[(c0 + cc) * 16 + j];
      if (v < best) { best = v; bidx = c0 + cc; }
    }
    bv[chunk][j] = best;
    bi[chunk][j] = bidx;
  }
  __syncthreads();
  if (t < 16) {
    float best = 3.4e38f;
    int bidx = 0;
    for (int c = 0; c < 16; ++c) {
      float v = bv[c][t];
      if (v < best) { best = v; bidx = bi[c][t]; }
    }
    idxs[t] = bidx;
  }
  __syncthreads();
  float sq = 0.f;
  for (int j = 0; j < 16; ++j) {
    float e = emb[(size_t)idxs[j] * 256 + t];
    q[(size_t)(T0 + j) * 256 + t] = e;
    float d = z[j][t] - e;
    sq += d * d;
  }
  __syncthreads();
  sc[t] = sq;
  __syncthreads();
  for (int k = 128; k > 0; k >>= 1) {
    if (t < k) sc[t] += sc[t + k];
    __syncthreads();
  }
  if (t == 0) atomicAdd(sse, sc[0]);
}

// ---------------- deconv2 + reconst loss ----------------
__global__ void __launch_bounds__(256) k_deconv2(const ushort_t* __restrict__ in,
                                                 const float* __restrict__ wT,
                                                 const float* __restrict__ bias,
                                                 const float* __restrict__ x,
                                                 float* __restrict__ dec,
                                                 float* __restrict__ sse) {
  __shared__ float patch[9216];
  __shared__ float red[768];
  int blk = blockIdx.x;
  int oy = blk & 31, n = blk >> 5;
  int t = threadIdx.x;
  int py = (oy + 1) & 1;
  int dy = (oy + 1 - py) >> 1;
  for (int it = 0; it < 36; ++it) {
    int s = it / 18, col = it - s * 18;
    int ix = col - 1, iy = dy - 1 + s;
    float v = 0.f;
    if ((unsigned)iy < 16u && (unsigned)ix < 16u)
      v = bs2f(in[(size_t)((n << 8) + iy * 16 + ix) * 256 + t]);
    patch[(t * 2 + s) * 18 + col] = v;
  }
  __syncthreads();
  int ox = t & 31, g = t >> 5;
  int px = (ox + 1) & 1;
  int dx = (ox + 1 - px) >> 1;
  int k00 = ((py + 2) * 4 + px + 2) * 3;
  int k01 = k00 - 6;
  int k10 = (py * 4 + px + 2) * 3;
  int k11 = k10 - 6;
  float a0 = 0.f, a1 = 0.f, a2 = 0.f;
  for (int ic = g * 32; ic < g * 32 + 32; ++ic) {
    const float* pp = patch + ic * 36;
    float v00 = pp[dx], v01 = pp[dx + 1], v10 = pp[18 + dx], v11 = pp[18 + dx + 1];
    const float* ww = wT + ic * 48;
    a0 += v00 * ww[k00 + 0] + v01 * ww[k01 + 0] + v10 * ww[k10 + 0] + v11 * ww[k11 + 0];
    a1 += v00 * ww[k00 + 1] + v01 * ww[k01 + 1] + v10 * ww[k10 + 1] + v11 * ww[k11 + 1];
    a2 += v00 * ww[k00 + 2] + v01 * ww[k01 + 2] + v10 * ww[k10 + 2] + v11 * ww[k11 + 2];
  }
  red[t * 3 + 0] = a0;
  red[t * 3 + 1] = a1;
  red[t * 3 + 2] = a2;
  __syncthreads();
  float sq = 0.f;
  if (t < 96) {
    int ox2 = t & 31, oc = t >> 5;
    float v = bias[oc];
#pragma unroll
    for (int g2 = 0; g2 < 8; ++g2) v += red[(g2 * 32 + ox2) * 3 + oc];
    int oi = ((n * 3 + oc) * 32 + oy) * 32 + ox2;
    dec[oi] = v;
    float d = v - x[oi];
    sq = d * d;
  }
  __syncthreads();
  red[t] = sq;
  __syncthreads();
  for (int k = 128; k > 0; k >>= 1) {
    if (t < k) red[t] += red[t + k];
    __syncthreads();
  }
  if (t == 0) atomicAdd(sse, red[0]);
}

__global__ void k_final(const float* __restrict__ acc, float* __restrict__ out) {
  if (threadIdx.x == 0 && blockIdx.x == 0) {
    float vq = acc[0] / 4194304.f;
    float rec = acc[1] / 786432.f;
    out[0] = rec + 2.f * vq;
    out[1] = rec;
    out[2] = vq;
    out[3] = vq;
  }
}

extern "C" void kernel_launch(void* const* d_in, const int* in_sizes, int n_in,
                              void* d_out, int out_size, void* d_ws, size_t ws_size,
                              hipStream_t stream) {
  (void)in_sizes; (void)n_in; (void)out_size; (void)ws_size;
  const float* x = (const float*)d_in[0];
  const float* ew1 = (const float*)d_in[1];
  const float* eb1 = (const float*)d_in[2];
  const float* ew2 = (const float*)d_in[3];
  const float* eb2 = (const float*)d_in[4];
  const float* rmsw = (const float*)d_in[5];
  const float* r3w = (const float*)d_in[6];
  const float* r3b = (const float*)d_in[7];
  const float* r1w = (const float*)d_in[8];
  const float* r1b = (const float*)d_in[9];
  const float* emb = (const float*)d_in[10];
  const float* dw1 = (const float*)d_in[11];
  const float* db1 = (const float*)d_in[12];
  const float* dw2 = (const float*)d_in[13];
  const float* db2 = (const float*)d_in[14];
  float* out = (float*)d_out;

  float* wsf = (float*)d_ws;
  float* P = wsf + OFF_P;
  float* enorm = wsf + OFF_ENORM;
  float* wTd2 = wsf + OFF_WTD2;
  float* acc = wsf + OFF_ACC;
  float* zrowf = wsf + OFF_ZROW;
  ushort_t* sb = (ushort_t*)(wsf + OFF_SHORT);
  ushort_t* H1H = sb + SO_H1H;
  ushort_t* H1L = sb + SO_H1L;
  float* Qf = (float*)(sb + SO_H1L);
  ushort_t* NBH = sb + SO_NBH;
  ushort_t* NBL = sb + SO_NBL;
  ushort_t* A1H = NBH;
  ushort_t* A1L = NBL;
  ushort_t* QB = NBL;
  ushort_t* W1H = sb + SO_W1H;
  ushort_t* W1L = sb + SO_W1L;
  ushort_t* W2H = sb + SO_W2H;
  ushort_t* W2L = sb + SO_W2L;
  ushort_t* W3EH = sb + SO_W3EH;
  ushort_t* W3EL = sb + SO_W3EL;
  ushort_t* W3D = sb + SO_W3D;
  ushort_t* W1REH = sb + SO_W1REH;
  ushort_t* W1REL = sb + SO_W1REL;
  ushort_t* W1RD = sb + SO_W1RD;
  ushort_t* WD1 = sb + SO_WD1;
  const ushort_t* zrow = (const ushort_t*)zrowf;
  const size_t RMS_LDS = 64 * 257 * sizeof(float);

  k_prep<<<34931, 256, 0, stream>>>(x, ew1, ew2, r3w, r1w, dw1, dw2, emb,
                                    W1H, W1L, W2H, W2L, W3EH, W3EL, W3D,
                                    W1REH, W1REL, W1RD, WD1, wTd2, enorm, acc,
                                    zrowf, A1H, A1L);

  // conv1 (split, K=64) -> H1H/H1L
  k_gemm<64, 0, 4, 1><<<dim3(1024, 2), 256, 0, stream>>>(
      A1H, A1L, W1H, W1L, eb1, nullptr, nullptr, H1H, H1L, zrow);
  // conv2 (split, K=4096) -> P
  k_gemm<4096, 1, 1, 1><<<dim3(256, 2), 256, 0, stream>>>(
      H1H, H1L, W2H, W2L, eb2, nullptr, P, nullptr, nullptr, zrow);

  for (int rb = 0; rb < 2; ++rb) {
    k_rmsnorm<1><<<256, 256, RMS_LDS, stream>>>(P, rmsw + (size_t)(rb * 2 + 0) * 16384, NBH, NBL);
    k_gemm<2304, 2, 2, 1><<<dim3(256, 2), 256, 0, stream>>>(
        NBH, NBL, W3EH + (size_t)rb * 589824, W3EL + (size_t)rb * 589824,
        r3b + rb * 256, P, Qf, nullptr, nullptr, zrow);
    k_rmsnorm<1><<<256, 256, RMS_LDS, stream>>>(Qf, rmsw + (size_t)(rb * 2 + 1) * 16384, NBH, NBL);
    k_gemm<256, 0, 2, 1><<<dim3(256, 2), 256, 0, stream>>>(
        NBH, NBL, W1REH + (size_t)rb * 65536, W1REL + (size_t)rb * 65536,
        r1b + rb * 256, Qf, P, nullptr, nullptr, zrow);
  }

  k_vq<<<1024, 256, 0, stream>>>(P, emb, enorm, Qf, acc + 0);

  for (int rb = 2; rb < 4; ++rb) {
    k_rmsnorm<0><<<256, 256, RMS_LDS, stream>>>(Qf, rmsw + (size_t)(rb * 2 + 0) * 16384, NBH, NBL);
    k_gemm<2304, 2, 2, 0><<<dim3(256, 2), 256, 0, stream>>>(
        NBH, nullptr, W3D + (size_t)(rb - 2) * 589824, nullptr,
        r3b + rb * 256, Qf, P, nullptr, nullptr, zrow);
    k_rmsnorm<0><<<256, 256, RMS_LDS, stream>>>(P, rmsw + (size_t)(rb * 2 + 1) * 16384, NBH, NBL);
    if (rb == 3) {
      k_gemm<256, 0, 5, 0><<<dim3(256, 2), 256, 0, stream>>>(
          NBH, nullptr, W1RD + (size_t)(rb - 2) * 65536, nullptr,
          r1b + rb * 256, P, Qf, QB, nullptr, zrow);
    } else {
      k_gemm<256, 0, 2, 0><<<dim3(256, 2), 256, 0, stream>>>(
          NBH, nullptr, W1RD + (size_t)(rb - 2) * 65536, nullptr,
          r1b + rb * 256, P, Qf, nullptr, nullptr, zrow);
    }
  }

  // deconv1 (plain, K=1024, 4 parity classes) -> H1H
  k_gemm<1024, 3, 3, 0><<<dim3(256, 2, 4), 256, 0, stream>>>(
      QB, nullptr, WD1, nullptr, db1, nullptr, nullptr, H1H, nullptr, zrow);

  k_deconv2<<<8192, 256, 0, stream>>>(H1H, wTd2, db2, x, out + 4, acc + 1);
  k_final<<<1, 64, 0, stream>>>(acc, out);
}

// Round 10
// 1292.369 us; speedup vs baseline: 1.3734x; 1.3734x over previous
//
#include <hip/hip_runtime.h>
#include <hip/hip_bf16.h>

typedef unsigned short ushort_t;
typedef __attribute__((ext_vector_type(8))) short short8v;
typedef __attribute__((ext_vector_type(4))) float f32x4;

__device__ __forceinline__ ushort_t f2bs(float v) {
  union { __hip_bfloat16 h; ushort_t u; } cv;
  cv.h = __float2bfloat16(v);
  return cv.u;
}
__device__ __forceinline__ float bs2f(ushort_t u) {
  union { ushort_t u; __hip_bfloat16 h; } cv;
  cv.u = u;
  return __bfloat162float(cv.h);
}

__device__ __forceinline__ void glds16(const ushort_t* g, ushort_t* l) {
  __builtin_amdgcn_global_load_lds(
      (const __attribute__((address_space(1))) unsigned int*)(uintptr_t)g,
      (__attribute__((address_space(3))) unsigned int*)(unsigned int)(uintptr_t)l,
      16, 0, 0);
}

// ---------------- workspace layout ----------------
static constexpr size_t OFF_P = 0;
static constexpr size_t OFF_ENORM = 4194304;
static constexpr size_t OFF_WTD2 = 4194816;
static constexpr size_t OFF_ACC = 4207360;
static constexpr size_t OFF_ZROW = 4207368;
static constexpr size_t OFF_SHORT = 4207432;
static constexpr size_t SO_H1H = 0;
static constexpr size_t SO_H1L = 16777216;
static constexpr size_t SO_NBH = 33554432;
static constexpr size_t SO_NBL = 37748736;
static constexpr size_t SO_W1H = 41943040;
static constexpr size_t SO_W1L = 41959424;
static constexpr size_t SO_W2H = 41975808;
static constexpr size_t SO_W2L = 43024384;
static constexpr size_t SO_W3EH = 44072960;
static constexpr size_t SO_W3EL = 45252608;
static constexpr size_t SO_W3D = 46432256;
static constexpr size_t SO_W1REH = 47611904;
static constexpr size_t SO_W1REL = 47742976;
static constexpr size_t SO_W1RD = 47874048;
static constexpr size_t SO_WD1 = 48005120;

__device__ __forceinline__ void split_store(float v, ushort_t* hi, ushort_t* lo, size_t i) {
  ushort_t h = f2bs(v);
  hi[i] = h;
  lo[i] = f2bs(v - bs2f(h));
}

// ---------------- fused prep ----------------
__global__ void __launch_bounds__(256) k_prep(
    const float* __restrict__ x, const float* __restrict__ ew1,
    const float* __restrict__ ew2, const float* __restrict__ r3w,
    const float* __restrict__ r1w, const float* __restrict__ dw1,
    const float* __restrict__ dw2, const float* __restrict__ emb,
    ushort_t* __restrict__ W1H, ushort_t* __restrict__ W1L,
    ushort_t* __restrict__ W2H, ushort_t* __restrict__ W2L,
    ushort_t* __restrict__ W3EH, ushort_t* __restrict__ W3EL,
    ushort_t* __restrict__ W3D, ushort_t* __restrict__ W1REH,
    ushort_t* __restrict__ W1REL, ushort_t* __restrict__ W1RD,
    ushort_t* __restrict__ WD1, float* __restrict__ wTd2,
    float* __restrict__ enorm, float* __restrict__ acc, float* __restrict__ zrow,
    ushort_t* __restrict__ A1H, ushort_t* __restrict__ A1L) {
  int b = blockIdx.x, t = threadIdx.x;
  if (b < 64) {
    int i = b * 256 + t;
    int oc = i >> 6, k = i & 63;
    float v = 0.f;
    if (k < 48) {
      int tap = k / 3, ic = k - 3 * tap;
      v = ew1[(oc * 3 + ic) * 16 + tap];
    }
    split_store(v, W1H, W1L, i);
  } else if (b < 4160) {
    int i = (b - 64) * 256 + t;
    int oc = i >> 12, k = i & 4095;
    int tap = k >> 8, ic = k & 255;
    split_store(ew2[(oc * 256 + ic) * 16 + tap], W2H, W2L, i);
  } else if (b < 8768) {
    int i = (b - 4160) * 256 + t;
    int rb = i / 589824, r2 = i - rb * 589824;
    int oc = r2 / 2304, k = r2 - oc * 2304;
    int r9 = k >> 8, ic = k & 255;
    split_store(r3w[((rb * 256 + oc) * 256 + ic) * 9 + r9], W3EH, W3EL, i);
  } else if (b < 13376) {
    int i = (b - 8768) * 256 + t;
    int rb = i / 589824, r2 = i - rb * 589824;
    int oc = r2 / 2304, k = r2 - oc * 2304;
    int r9 = k >> 8, ic = k & 255;
    W3D[i] = f2bs(r3w[(((rb + 2) * 256 + oc) * 256 + ic) * 9 + r9]);
  } else if (b < 13888) {
    int i = (b - 13376) * 256 + t;
    split_store(r1w[i], W1REH, W1REL, i);
  } else if (b < 14400) {
    int i = (b - 13888) * 256 + t;
    W1RD[i] = f2bs(r1w[2 * 65536 + i]);
  } else if (b < 18496) {
    int i = (b - 14400) * 256 + t;
    int cls = i >> 18, r2 = i & 262143;
    int oc = r2 >> 10, k = r2 & 1023;
    int tap = k >> 8, ic = k & 255;
    int s = tap >> 1, sx = tap & 1;
    int py = cls >> 1, px = cls & 1;
    int ky = py + 2 - 2 * s, kx = px + 2 - 2 * sx;
    WD1[i] = f2bs(dw1[(ic * 256 + oc) * 16 + ky * 4 + kx]);
  } else if (b < 18544) {
    int i = (b - 18496) * 256 + t;
    if (i < 12288) {
      int kyx = i & 15;
      int r = i >> 4;
      int oc = r % 3;
      int ic = r / 3;
      wTd2[(ic * 16 + kyx) * 3 + oc] = dw2[i];
    }
  } else if (b < 18546) {
    int e = (b - 18544) * 256 + t;
    float s = 0.f;
    for (int c = 0; c < 256; ++c) {
      float v = emb[e * 256 + c];
      s += v * v;
    }
    enorm[e] = s;
  } else if (b == 18546) {
    if (t < 2) acc[t] = 0.f;
    if (t < 64) zrow[t] = 0.f;
  } else {
    int i = (b - 18547) * 256 + t;
    int t1 = i >> 6, k = i & 63;
    float v = 0.f;
    if (k < 48) {
      int tap = k / 3, ic = k - 3 * tap;
      int n = t1 >> 8, oy = (t1 >> 4) & 15, ox = t1 & 15;
      int ky = tap >> 2, kx = tap & 3;
      int iy = 2 * oy - 1 + ky, ix = 2 * ox - 1 + kx;
      if ((unsigned)iy < 32u && (unsigned)ix < 32u)
        v = x[((n * 3 + ic) * 32 + iy) * 32 + ix];
    }
    split_store(v, A1H, A1L, i);
  }
}

// ---------------- MFMA GEMM (r5 structure, DB sub-windows per barrier) ----------
// BM=128, BN=64, 4 waves, wave tile 64x32 (4x2 frags). Planes chunk-major
// (conflict-free ds_read_b128). DB=2: stage 2 sub-windows (12 glds/wave), ONE
// barrier pair covers both -> half the vmcnt(0) barrier drains of r5.
// STYLE 1 (split, sub=32): AhBh+AlBh+AhBl = 24 MFMA/wave/sub
// STYLE 0 (plain, sub=64): 16 MFMA/wave/sub
// MODE: 0=direct A, 1=conv2 im2col (16x16 grid), 2=res3 3x3 im2col (8x8),
//       3=deconv1 tap (8x8, cls=blockIdx.z)
// EPI: 1=relu->f32, 2=res+relu->f32, 3=deconv1 remap relu->bf16,
//      4=relu->split bf16, 5=res+relu->f32 AND bf16 copy
template <int MODE, int EPI, int STYLE, int DB>
__global__ __launch_bounds__(256) void k_gemm(const ushort_t* __restrict__ Ah,
                                              const ushort_t* __restrict__ Al,
                                              const ushort_t* __restrict__ Bh,
                                              const ushort_t* __restrict__ Bl, int K,
                                              const float* __restrict__ bias,
                                              const float* __restrict__ res,
                                              float* __restrict__ outf,
                                              ushort_t* __restrict__ outb,
                                              ushort_t* __restrict__ outb2,
                                              const ushort_t* __restrict__ zrow) {
  __shared__ __align__(16) ushort_t A0[DB][128 * 32];
  __shared__ __align__(16) ushort_t A1s[DB][128 * 32];
  __shared__ __align__(16) ushort_t B0[DB][64 * 32];
  __shared__ __align__(16) ushort_t B1[DB][64 * 32];
  const int t = threadIdx.x;
  const int w = t >> 6, l = t & 63;
  const int M0 = blockIdx.x * 128, N0 = blockIdx.y * 64;
  int py = 0, px = 0;
  const ushort_t* Bb = Bh;
  if (MODE == 3) {
    int cls = blockIdx.z;
    py = cls >> 1;
    px = cls & 1;
    Bb = Bh + (size_t)cls * 262144;
  }
  const int srow = l & 15, chunk = l >> 4;
  const int tok1 = M0 + w * 32 + srow, tok2 = tok1 + 16;
  const int bR = N0 + w * 16 + srow;
  const int fr = l & 15, quad = l >> 4;
  const int m_off = (w & 1) * 64, n_off = (w >> 1) * 32;
  const int mset = (m_off >> 4), nset = (n_off >> 4);

  f32x4 acc[4][2];
#pragma unroll
  for (int i = 0; i < 4; ++i)
#pragma unroll
    for (int j = 0; j < 2; ++j) acc[i][j] = (f32x4){0.f, 0.f, 0.f, 0.f};

  const int n1 = tok1 >> 6, oy1 = (tok1 >> 3) & 7, ox1 = tok1 & 7;
  const int n2 = tok2 >> 6, oy2 = (tok2 >> 3) & 7, ox2 = tok2 & 7;
  const ushort_t* zp = zrow + chunk * 8;

  const int SUB = (STYLE == 1) ? 32 : 64;
  const int STEP = DB * SUB;
  for (int k0 = 0; k0 < K; k0 += STEP) {
#pragma unroll
    for (int d = 0; d < DB; ++d) {
      const int kk = k0 + d * SUB;
      const ushort_t *p1, *p2, *q1, *q2;
      if (MODE == 0) {
        size_t o1 = (size_t)tok1 * K + kk + chunk * 8;
        size_t o2 = (size_t)tok2 * K + kk + chunk * 8;
        p1 = Ah + o1;
        p2 = Ah + o2;
        q1 = (STYLE == 1) ? Al + o1 : Ah + o1 + 32;
        q2 = (STYLE == 1) ? Al + o2 : Ah + o2 + 32;
      } else {
        int tap = kk >> 8, kin = (kk & 255) + chunk * 8;
        int iy1, ix1, iy2, ix2;
        unsigned lim;
        if (MODE == 1) {
          int ky = tap >> 2, kx = tap & 3;
          iy1 = 2 * oy1 - 1 + ky; ix1 = 2 * ox1 - 1 + kx;
          iy2 = 2 * oy2 - 1 + ky; ix2 = 2 * ox2 - 1 + kx;
          lim = 16u;
        } else if (MODE == 2) {
          int ky = tap / 3, kx = tap - ky * 3;
          iy1 = oy1 - 1 + ky; ix1 = ox1 - 1 + kx;
          iy2 = oy2 - 1 + ky; ix2 = ox2 - 1 + kx;
          lim = 8u;
        } else {
          int s = tap >> 1, sx = tap & 1;
          iy1 = oy1 + s - py; ix1 = ox1 + sx - px;
          iy2 = oy2 + s - py; ix2 = ox2 + sx - px;
          lim = 8u;
        }
        bool v1 = ((unsigned)iy1 < lim && (unsigned)ix1 < lim);
        bool v2 = ((unsigned)iy2 < lim && (unsigned)ix2 < lim);
        size_t r1, r2;
        if (MODE == 1) {
          r1 = (size_t)(((n1 << 8) + (iy1 << 4) + ix1)) << 8;
          r2 = (size_t)(((n2 << 8) + (iy2 << 4) + ix2)) << 8;
        } else {
          r1 = (size_t)(((n1 << 6) + (iy1 << 3) + ix1)) << 8;
          r2 = (size_t)(((n2 << 6) + (iy2 << 3) + ix2)) << 8;
        }
        if (STYLE == 1) {
          p1 = v1 ? Ah + r1 + kin : zp;
          p2 = v2 ? Ah + r2 + kin : zp;
          q1 = v1 ? Al + r1 + kin : zp;
          q2 = v2 ? Al + r2 + kin : zp;
        } else {
          p1 = v1 ? Ah + r1 + kin : zp;
          p2 = v2 ? Ah + r2 + kin : zp;
          q1 = v1 ? Ah + r1 + kin + 32 : zp;
          q2 = v2 ? Ah + r2 + kin + 32 : zp;
        }
      }
      size_t bo = (size_t)bR * K + kk + chunk * 8;
      glds16(p1, A0[d] + w * 1024);
      glds16(p2, A0[d] + w * 1024 + 512);
      glds16(q1, A1s[d] + w * 1024);
      glds16(q2, A1s[d] + w * 1024 + 512);
      glds16(Bb + bo, B0[d] + w * 512);
      glds16((STYLE == 1) ? (Bl + bo) : (Bb + bo + 32), B1[d] + w * 512);
    }
    __syncthreads();
#pragma unroll
    for (int d = 0; d < DB; ++d) {
      short8v af0[4], af1[4], bf0[2], bf1[2];
#pragma unroll
      for (int mi = 0; mi < 4; ++mi) {
        af0[mi] = *(const short8v*)(A0[d] + (mset + mi) * 512 + quad * 128 + fr * 8);
        af1[mi] = *(const short8v*)(A1s[d] + (mset + mi) * 512 + quad * 128 + fr * 8);
      }
#pragma unroll
      for (int nj = 0; nj < 2; ++nj) {
        bf0[nj] = *(const short8v*)(B0[d] + (nset + nj) * 512 + quad * 128 + fr * 8);
        bf1[nj] = *(const short8v*)(B1[d] + (nset + nj) * 512 + quad * 128 + fr * 8);
      }
#pragma unroll
      for (int mi = 0; mi < 4; ++mi)
#pragma unroll
        for (int nj = 0; nj < 2; ++nj) {
          acc[mi][nj] =
              __builtin_amdgcn_mfma_f32_16x16x32_bf16(af0[mi], bf0[nj], acc[mi][nj], 0, 0, 0);
          if (STYLE == 1) {
            acc[mi][nj] =
                __builtin_amdgcn_mfma_f32_16x16x32_bf16(af1[mi], bf0[nj], acc[mi][nj], 0, 0, 0);
            acc[mi][nj] =
                __builtin_amdgcn_mfma_f32_16x16x32_bf16(af0[mi], bf1[nj], acc[mi][nj], 0, 0, 0);
          } else {
            acc[mi][nj] =
                __builtin_amdgcn_mfma_f32_16x16x32_bf16(af1[mi], bf1[nj], acc[mi][nj], 0, 0, 0);
          }
        }
    }
    __syncthreads();
  }

#pragma unroll
  for (int mi = 0; mi < 4; ++mi) {
    int mrow = m_off + mi * 16 + (l >> 4) * 4;
#pragma unroll
    for (int nj = 0; nj < 2; ++nj) {
      int col = N0 + n_off + nj * 16 + fr;
      float bv = bias[col];
#pragma unroll
      for (int i = 0; i < 4; ++i) {
        int m = M0 + mrow + i;
        float v = fmaxf(acc[mi][nj][i] + bv, 0.f);
        if (EPI == 1) {
          outf[(size_t)m * 256 + col] = v;
        } else if (EPI == 2) {
          size_t o = (size_t)m * 256 + col;
          outf[o] = res[o] + v;
        } else if (EPI == 3) {
          int nn = m >> 6, jj = (m >> 3) & 7, ii = m & 7;
          int oy = 2 * jj + 1 - py, ox = 2 * ii + 1 - px;
          outb[(size_t)((nn << 8) + oy * 16 + ox) * 256 + col] = f2bs(v);
        } else if (EPI == 4) {
          size_t o = (size_t)m * 256 + col;
          ushort_t h = f2bs(v);
          outb[o] = h;
          outb2[o] = f2bs(v - bs2f(h));
        } else {  // EPI 5
          size_t o = (size_t)m * 256 + col;
          float vv = res[o] + v;
          outf[o] = vv;
          outb[o] = f2bs(vv);
        }
      }
    }
  }
}

// ---------------- fused rmsnorm (coalesced rmsw via transposed LDS stage) ----------
template <int SPLIT>
__global__ void __launch_bounds__(256) k_rmsnorm(const float* __restrict__ in,
                                                 const float* __restrict__ rmsw,
                                                 ushort_t* __restrict__ NBh,
                                                 ushort_t* __restrict__ NBl) {
  extern __shared__ float wT[];  // 64*257 floats
  __shared__ float sd[256];
  __shared__ float s_scale;
  int n = blockIdx.x, t = threadIdx.x;
  const float* p = in + (size_t)n * 16384;
  for (int k = 0; k < 64; ++k) {
    int i = k * 256 + t;  // i = c*64 + j
    wT[(i & 63) * 257 + (i >> 6)] = rmsw[i];
  }
  float s = 0.f;
  const float4* p4 = (const float4*)p;
  for (int i = t; i < 4096; i += 256) {
    float4 v = p4[i];
    s += v.x * v.x + v.y * v.y + v.z * v.z + v.w * v.w;
  }
  sd[t] = s;
  __syncthreads();
  for (int k = 128; k > 0; k >>= 1) {
    if (t < k) sd[t] += sd[t + k];
    __syncthreads();
  }
  if (t == 0) s_scale = 1.0f / sqrtf(sd[0] / 16384.f + 1.1920929e-07f);
  __syncthreads();
  float scale = s_scale;
  ushort_t* oh = NBh + (size_t)n * 16384;
  ushort_t* ol = NBl + (size_t)n * 16384;
  for (int j = 0; j < 64; ++j) {
    int i = j * 256 + t;
    float v = p[i] * scale * wT[j * 257 + t];
    ushort_t h = f2bs(v);
    oh[i] = h;
    if (SPLIT) ol[i] = f2bs(v - bs2f(h));
  }
}

// ---------------- VQ ----------------
__global__ void __launch_bounds__(256) k_vq(const float* __restrict__ enc,
                                            const float* __restrict__ emb,
                                            const float* __restrict__ enorm,
                                            float* __restrict__ q, float* __restrict__ sse) {
  __shared__ float z[16][256];
  __shared__ float sc[512 * 16];
  __shared__ float bv[16][16];
  __shared__ int bi[16][16];
  __shared__ int idxs[16];
  int T0 = blockIdx.x * 16;
  int t = threadIdx.x;
  for (int j = 0; j < 16; ++j) z[j][t] = enc[(size_t)(T0 + j) * 256 + t];
  __syncthreads();
  float d0[16], d1[16];
#pragma unroll
  for (int j = 0; j < 16; ++j) { d0[j] = 0.f; d1[j] = 0.f; }
  const float4* e0 = (const float4*)(emb + (size_t)t * 256);
  const float4* e1 = (const float4*)(emb + (size_t)(t + 256) * 256);
  for (int c4 = 0; c4 < 64; ++c4) {
    float4 ea = e0[c4];
    float4 eb = e1[c4];
#pragma unroll
    for (int j = 0; j < 16; ++j) {
      float4 zv = *(const float4*)&z[j][c4 * 4];
      d0[j] += zv.x * ea.x + zv.y * ea.y + zv.z * ea.z + zv.w * ea.w;
      d1[j] += zv.x * eb.x + zv.y * eb.y + zv.z * eb.z + zv.w * eb.w;
    }
  }
  float en0 = enorm[t], en1 = enorm[t + 256];
#pragma unroll
  for (int j = 0; j < 16; ++j) {
    sc[t * 16 + j] = en0 - 2.f * d0[j];
    sc[(t + 256) * 16 + j] = en1 - 2.f * d1[j];
  }
  __syncthreads();
  {
    int j = t & 15, chunk = t >> 4;
    float best = 3.4e38f;
    int bidx = 0;
    int c0 = chunk * 32;
    for (int cc = 0; cc < 32; ++cc) {
      float v = sc[(c0 + cc) * 16 + j];
      if (v < best) { best = v; bidx = c0 + cc; }
    }
    bv[chunk][j] = best;
    bi[chunk][j] = bidx;
  }
  __syncthreads();
  if (t < 16) {
    float best = 3.4e38f;
    int bidx = 0;
    for (int c = 0; c < 16; ++c) {
      float v = bv[c][t];
      if (v < best) { best = v; bidx = bi[c][t]; }
    }
    idxs[t] = bidx;
  }
  __syncthreads();
  float sq = 0.f;
  for (int j = 0; j < 16; ++j) {
    float e = emb[(size_t)idxs[j] * 256 + t];
    q[(size_t)(T0 + j) * 256 + t] = e;
    float d = z[j][t] - e;
    sq += d * d;
  }
  __syncthreads();
  sc[t] = sq;
  __syncthreads();
  for (int k = 128; k > 0; k >>= 1) {
    if (t < k) sc[t] += sc[t + k];
    __syncthreads();
  }
  if (t == 0) atomicAdd(sse, sc[0]);
}

// ---------------- deconv2 + reconst loss ----------------
__global__ void __launch_bounds__(256) k_deconv2(const ushort_t* __restrict__ in,
                                                 const float* __restrict__ wT,
                                                 const float* __restrict__ bias,
                                                 const float* __restrict__ x,
                                                 float* __restrict__ dec,
                                                 float* __restrict__ sse) {
  __shared__ float patch[9216];
  __shared__ float red[768];
  int blk = blockIdx.x;
  int oy = blk & 31, n = blk >> 5;
  int t = threadIdx.x;
  int py = (oy + 1) & 1;
  int dy = (oy + 1 - py) >> 1;
  for (int it = 0; it < 36; ++it) {
    int s = it / 18, col = it - s * 18;
    int ix = col - 1, iy = dy - 1 + s;
    float v = 0.f;
    if ((unsigned)iy < 16u && (unsigned)ix < 16u)
      v = bs2f(in[(size_t)((n << 8) + iy * 16 + ix) * 256 + t]);
    patch[(t * 2 + s) * 18 + col] = v;
  }
  __syncthreads();
  int ox = t & 31, g = t >> 5;
  int px = (ox + 1) & 1;
  int dx = (ox + 1 - px) >> 1;
  int k00 = ((py + 2) * 4 + px + 2) * 3;
  int k01 = k00 - 6;
  int k10 = (py * 4 + px + 2) * 3;
  int k11 = k10 - 6;
  float a0 = 0.f, a1 = 0.f, a2 = 0.f;
  for (int ic = g * 32; ic < g * 32 + 32; ++ic) {
    const float* pp = patch + ic * 36;
    float v00 = pp[dx], v01 = pp[dx + 1], v10 = pp[18 + dx], v11 = pp[18 + dx + 1];
    const float* ww = wT + ic * 48;
    a0 += v00 * ww[k00 + 0] + v01 * ww[k01 + 0] + v10 * ww[k10 + 0] + v11 * ww[k11 + 0];
    a1 += v00 * ww[k00 + 1] + v01 * ww[k01 + 1] + v10 * ww[k10 + 1] + v11 * ww[k11 + 1];
    a2 += v00 * ww[k00 + 2] + v01 * ww[k01 + 2] + v10 * ww[k10 + 2] + v11 * ww[k11 + 2];
  }
  red[t * 3 + 0] = a0;
  red[t * 3 + 1] = a1;
  red[t * 3 + 2] = a2;
  __syncthreads();
  float sq = 0.f;
  if (t < 96) {
    int ox2 = t & 31, oc = t >> 5;
    float v = bias[oc];
#pragma unroll
    for (int g2 = 0; g2 < 8; ++g2) v += red[(g2 * 32 + ox2) * 3 + oc];
    int oi = ((n * 3 + oc) * 32 + oy) * 32 + ox2;
    dec[oi] = v;
    float d = v - x[oi];
    sq = d * d;
  }
  __syncthreads();
  red[t] = sq;
  __syncthreads();
  for (int k = 128; k > 0; k >>= 1) {
    if (t < k) red[t] += red[t + k];
    __syncthreads();
  }
  if (t == 0) atomicAdd(sse, red[0]);
}

__global__ void k_final(const float* __restrict__ acc, float* __restrict__ out) {
  if (threadIdx.x == 0 && blockIdx.x == 0) {
    float vq = acc[0] / 4194304.f;
    float rec = acc[1] / 786432.f;
    out[0] = rec + 2.f * vq;
    out[1] = rec;
    out[2] = vq;
    out[3] = vq;
  }
}

extern "C" void kernel_launch(void* const* d_in, const int* in_sizes, int n_in,
                              void* d_out, int out_size, void* d_ws, size_t ws_size,
                              hipStream_t stream) {
  (void)in_sizes; (void)n_in; (void)out_size; (void)ws_size;
  const float* x = (const float*)d_in[0];
  const float* ew1 = (const float*)d_in[1];
  const float* eb1 = (const float*)d_in[2];
  const float* ew2 = (const float*)d_in[3];
  const float* eb2 = (const float*)d_in[4];
  const float* rmsw = (const float*)d_in[5];
  const float* r3w = (const float*)d_in[6];
  const float* r3b = (const float*)d_in[7];
  const float* r1w = (const float*)d_in[8];
  const float* r1b = (const float*)d_in[9];
  const float* emb = (const float*)d_in[10];
  const float* dw1 = (const float*)d_in[11];
  const float* db1 = (const float*)d_in[12];
  const float* dw2 = (const float*)d_in[13];
  const float* db2 = (const float*)d_in[14];
  float* out = (float*)d_out;

  float* wsf = (float*)d_ws;
  float* P = wsf + OFF_P;
  float* enorm = wsf + OFF_ENORM;
  float* wTd2 = wsf + OFF_WTD2;
  float* acc = wsf + OFF_ACC;
  float* zrowf = wsf + OFF_ZROW;
  ushort_t* sb = (ushort_t*)(wsf + OFF_SHORT);
  ushort_t* H1H = sb + SO_H1H;
  ushort_t* H1L = sb + SO_H1L;
  float* Qf = (float*)(sb + SO_H1L);
  ushort_t* NBH = sb + SO_NBH;
  ushort_t* NBL = sb + SO_NBL;
  ushort_t* A1H = NBH;
  ushort_t* A1L = NBL;
  ushort_t* QB = NBL;
  ushort_t* W1H = sb + SO_W1H;
  ushort_t* W1L = sb + SO_W1L;
  ushort_t* W2H = sb + SO_W2H;
  ushort_t* W2L = sb + SO_W2L;
  ushort_t* W3EH = sb + SO_W3EH;
  ushort_t* W3EL = sb + SO_W3EL;
  ushort_t* W3D = sb + SO_W3D;
  ushort_t* W1REH = sb + SO_W1REH;
  ushort_t* W1REL = sb + SO_W1REL;
  ushort_t* W1RD = sb + SO_W1RD;
  ushort_t* WD1 = sb + SO_WD1;
  const ushort_t* zrow = (const ushort_t*)zrowf;
  const size_t RMS_LDS = 64 * 257 * sizeof(float);

  k_prep<<<34931, 256, 0, stream>>>(x, ew1, ew2, r3w, r1w, dw1, dw2, emb,
                                    W1H, W1L, W2H, W2L, W3EH, W3EL, W3D,
                                    W1REH, W1REL, W1RD, WD1, wTd2, enorm, acc,
                                    zrowf, A1H, A1L);

  // conv1 (split, K=64 -> 1 barrier window)
  k_gemm<0, 4, 1, 2><<<dim3(512, 4), 256, 0, stream>>>(A1H, A1L, W1H, W1L, 64, eb1,
                                                       nullptr, nullptr, H1H, H1L, zrow);
  // conv2 (split, K=4096 -> 64 windows)
  k_gemm<1, 1, 1, 2><<<dim3(128, 4), 256, 0, stream>>>(H1H, H1L, W2H, W2L, 4096, eb2,
                                                       nullptr, P, nullptr, nullptr, zrow);
  for (int rb = 0; rb < 2; ++rb) {
    k_rmsnorm<1><<<256, 256, RMS_LDS, stream>>>(P, rmsw + (size_t)(rb * 2 + 0) * 16384, NBH, NBL);
    k_gemm<2, 2, 1, 2><<<dim3(128, 4), 256, 0, stream>>>(
        NBH, NBL, W3EH + (size_t)rb * 589824, W3EL + (size_t)rb * 589824, 2304,
        r3b + rb * 256, P, Qf, nullptr, nullptr, zrow);
    k_rmsnorm<1><<<256, 256, RMS_LDS, stream>>>(Qf, rmsw + (size_t)(rb * 2 + 1) * 16384, NBH, NBL);
    k_gemm<0, 2, 1, 2><<<dim3(128, 4), 256, 0, stream>>>(
        NBH, NBL, W1REH + (size_t)rb * 65536, W1REL + (size_t)rb * 65536, 256,
        r1b + rb * 256, Qf, P, nullptr, nullptr, zrow);
  }

  k_vq<<<1024, 256, 0, stream>>>(P, emb, enorm, Qf, acc + 0);

  for (int rb = 2; rb < 4; ++rb) {
    k_rmsnorm<0><<<256, 256, RMS_LDS, stream>>>(Qf, rmsw + (size_t)(rb * 2 + 0) * 16384, NBH, NBL);
    k_gemm<2, 2, 0, 2><<<dim3(128, 4), 256, 0, stream>>>(
        NBH, nullptr, W3D + (size_t)(rb - 2) * 589824, nullptr, 2304,
        r3b + rb * 256, Qf, P, nullptr, nullptr, zrow);
    k_rmsnorm<0><<<256, 256, RMS_LDS, stream>>>(P, rmsw + (size_t)(rb * 2 + 1) * 16384, NBH, NBL);
    if (rb == 3) {
      k_gemm<0, 5, 0, 2><<<dim3(128, 4), 256, 0, stream>>>(
          NBH, nullptr, W1RD + (size_t)(rb - 2) * 65536, nullptr, 256,
          r1b + rb * 256, P, Qf, QB, nullptr, zrow);
    } else {
      k_gemm<0, 2, 0, 2><<<dim3(128, 4), 256, 0, stream>>>(
          NBH, nullptr, W1RD + (size_t)(rb - 2) * 65536, nullptr, 256,
          r1b + rb * 256, P, Qf, nullptr, nullptr, zrow);
    }
  }

  // deconv1 (plain, K=1024, 4 parity classes -> 8 windows)
  k_gemm<3, 3, 0, 2><<<dim3(128, 4, 4), 256, 0, stream>>>(QB, nullptr, WD1, nullptr, 1024, db1,
                                                          nullptr, nullptr, H1H, nullptr, zrow);

  k_deconv2<<<8192, 256, 0, stream>>>(H1H, wTd2, db2, x, out + 4, acc + 1);
  k_final<<<1, 64, 0, stream>>>(acc, out);
}

// Round 11
// 1288.727 us; speedup vs baseline: 1.3773x; 1.0028x over previous
//
#include <hip/hip_runtime.h>
#include <hip/hip_bf16.h>

typedef unsigned short ushort_t;
typedef __attribute__((ext_vector_type(8))) short short8v;
typedef __attribute__((ext_vector_type(4))) float f32x4;

__device__ __forceinline__ ushort_t f2bs(float v) {
  union { __hip_bfloat16 h; ushort_t u; } cv;
  cv.h = __float2bfloat16(v);
  return cv.u;
}
__device__ __forceinline__ float bs2f(ushort_t u) {
  union { ushort_t u; __hip_bfloat16 h; } cv;
  cv.u = u;
  return __bfloat162float(cv.h);
}

__device__ __forceinline__ void glds16(const ushort_t* g, ushort_t* l) {
  __builtin_amdgcn_global_load_lds(
      (const __attribute__((address_space(1))) unsigned int*)(uintptr_t)g,
      (__attribute__((address_space(3))) unsigned int*)(unsigned int)(uintptr_t)l,
      16, 0, 0);
}

// ---------------- workspace layout ----------------
static constexpr size_t OFF_P = 0;
static constexpr size_t OFF_ENORM = 4194304;
static constexpr size_t OFF_WTD2 = 4194816;
static constexpr size_t OFF_ACC = 4207360;
static constexpr size_t OFF_ZROW = 4207368;
static constexpr size_t OFF_SHORT = 4207432;
static constexpr size_t SO_H1H = 0;
static constexpr size_t SO_H1L = 16777216;
static constexpr size_t SO_NBH = 33554432;
static constexpr size_t SO_NBL = 37748736;
static constexpr size_t SO_W1H = 41943040;
static constexpr size_t SO_W1L = 41959424;
static constexpr size_t SO_W2H = 41975808;
static constexpr size_t SO_W2L = 43024384;
static constexpr size_t SO_W3EH = 44072960;
static constexpr size_t SO_W3EL = 45252608;
static constexpr size_t SO_W3D = 46432256;
static constexpr size_t SO_W1REH = 47611904;
static constexpr size_t SO_W1REL = 47742976;
static constexpr size_t SO_W1RD = 47874048;
static constexpr size_t SO_WD1 = 48005120;

__device__ __forceinline__ void split_store(float v, ushort_t* hi, ushort_t* lo, size_t i) {
  ushort_t h = f2bs(v);
  hi[i] = h;
  lo[i] = f2bs(v - bs2f(h));
}

// ---------------- fused prep ----------------
__global__ void __launch_bounds__(256) k_prep(
    const float* __restrict__ x, const float* __restrict__ ew1,
    const float* __restrict__ ew2, const float* __restrict__ r3w,
    const float* __restrict__ r1w, const float* __restrict__ dw1,
    const float* __restrict__ dw2, const float* __restrict__ emb,
    ushort_t* __restrict__ W1H, ushort_t* __restrict__ W1L,
    ushort_t* __restrict__ W2H, ushort_t* __restrict__ W2L,
    ushort_t* __restrict__ W3EH, ushort_t* __restrict__ W3EL,
    ushort_t* __restrict__ W3D, ushort_t* __restrict__ W1REH,
    ushort_t* __restrict__ W1REL, ushort_t* __restrict__ W1RD,
    ushort_t* __restrict__ WD1, float* __restrict__ wTd2,
    float* __restrict__ enorm, float* __restrict__ acc, float* __restrict__ zrow,
    ushort_t* __restrict__ A1H, ushort_t* __restrict__ A1L) {
  int b = blockIdx.x, t = threadIdx.x;
  if (b < 64) {
    int i = b * 256 + t;
    int oc = i >> 6, k = i & 63;
    float v = 0.f;
    if (k < 48) {
      int tap = k / 3, ic = k - 3 * tap;
      v = ew1[(oc * 3 + ic) * 16 + tap];
    }
    split_store(v, W1H, W1L, i);
  } else if (b < 4160) {
    int i = (b - 64) * 256 + t;
    int oc = i >> 12, k = i & 4095;
    int tap = k >> 8, ic = k & 255;
    split_store(ew2[(oc * 256 + ic) * 16 + tap], W2H, W2L, i);
  } else if (b < 8768) {
    int i = (b - 4160) * 256 + t;
    int rb = i / 589824, r2 = i - rb * 589824;
    int oc = r2 / 2304, k = r2 - oc * 2304;
    int r9 = k >> 8, ic = k & 255;
    split_store(r3w[((rb * 256 + oc) * 256 + ic) * 9 + r9], W3EH, W3EL, i);
  } else if (b < 13376) {
    int i = (b - 8768) * 256 + t;
    int rb = i / 589824, r2 = i - rb * 589824;
    int oc = r2 / 2304, k = r2 - oc * 2304;
    int r9 = k >> 8, ic = k & 255;
    W3D[i] = f2bs(r3w[(((rb + 2) * 256 + oc) * 256 + ic) * 9 + r9]);
  } else if (b < 13888) {
    int i = (b - 13376) * 256 + t;
    split_store(r1w[i], W1REH, W1REL, i);
  } else if (b < 14400) {
    int i = (b - 13888) * 256 + t;
    W1RD[i] = f2bs(r1w[2 * 65536 + i]);
  } else if (b < 18496) {
    int i = (b - 14400) * 256 + t;
    int cls = i >> 18, r2 = i & 262143;
    int oc = r2 >> 10, k = r2 & 1023;
    int tap = k >> 8, ic = k & 255;
    int s = tap >> 1, sx = tap & 1;
    int py = cls >> 1, px = cls & 1;
    int ky = py + 2 - 2 * s, kx = px + 2 - 2 * sx;
    WD1[i] = f2bs(dw1[(ic * 256 + oc) * 16 + ky * 4 + kx]);
  } else if (b < 18544) {
    int i = (b - 18496) * 256 + t;
    if (i < 12288) {
      int kyx = i & 15;
      int r = i >> 4;
      int oc = r % 3;
      int ic = r / 3;
      wTd2[(ic * 16 + kyx) * 3 + oc] = dw2[i];
    }
  } else if (b < 18546) {
    int e = (b - 18544) * 256 + t;
    float s = 0.f;
    for (int c = 0; c < 256; ++c) {
      float v = emb[e * 256 + c];
      s += v * v;
    }
    enorm[e] = s;
  } else if (b == 18546) {
    if (t < 2) acc[t] = 0.f;
    if (t < 64) zrow[t] = 0.f;
  } else {
    int i = (b - 18547) * 256 + t;
    int t1 = i >> 6, k = i & 63;
    float v = 0.f;
    if (k < 48) {
      int tap = k / 3, ic = k - 3 * tap;
      int n = t1 >> 8, oy = (t1 >> 4) & 15, ox = t1 & 15;
      int ky = tap >> 2, kx = tap & 3;
      int iy = 2 * oy - 1 + ky, ix = 2 * ox - 1 + kx;
      if ((unsigned)iy < 32u && (unsigned)ix < 32u)
        v = x[((n * 3 + ic) * 32 + iy) * 32 + ix];
    }
    split_store(v, A1H, A1L, i);
  }
}

// ---------------- MFMA GEMM (r10 structure + XCD-aware swizzle) ----------
// BM=128, BN=64, 4 waves, wave tile 64x32. DB=2 sub-windows per barrier.
// SWZ=1: 1D grid (4*Mtiles); b -> m=(b>>5)*8+(b&7), n=(b>>3)&3. The 4 N-tiles
// sharing one A-tile land on the SAME XCD (b mod 8 invariant) within a
// 32-block dispatch window -> A-tile underlying data stays in that XCD's L2.
// STYLE 1 (split, sub=32): AhBh+AlBh+AhBl = 24 MFMA/wave/sub
// STYLE 0 (plain, sub=64): 16 MFMA/wave/sub
// MODE: 0=direct A, 1=conv2 im2col, 2=res3 3x3 im2col, 3=deconv1 (z=class)
// EPI: 1=relu->f32, 2=res+relu->f32, 3=deconv1 remap relu->bf16,
//      4=relu->split bf16, 5=res+relu->f32 AND bf16 copy
template <int MODE, int EPI, int STYLE, int DB, int SWZ>
__global__ __launch_bounds__(256) void k_gemm(const ushort_t* __restrict__ Ah,
                                              const ushort_t* __restrict__ Al,
                                              const ushort_t* __restrict__ Bh,
                                              const ushort_t* __restrict__ Bl, int K,
                                              const float* __restrict__ bias,
                                              const float* __restrict__ res,
                                              float* __restrict__ outf,
                                              ushort_t* __restrict__ outb,
                                              ushort_t* __restrict__ outb2,
                                              const ushort_t* __restrict__ zrow) {
  __shared__ __align__(16) ushort_t A0[DB][128 * 32];
  __shared__ __align__(16) ushort_t A1s[DB][128 * 32];
  __shared__ __align__(16) ushort_t B0[DB][64 * 32];
  __shared__ __align__(16) ushort_t B1[DB][64 * 32];
  const int t = threadIdx.x;
  const int w = t >> 6, l = t & 63;
  int M0, N0;
  if (SWZ) {
    int b = blockIdx.x;
    M0 = (((b >> 5) << 3) | (b & 7)) * 128;
    N0 = ((b >> 3) & 3) * 64;
  } else {
    M0 = blockIdx.x * 128;
    N0 = blockIdx.y * 64;
  }
  int py = 0, px = 0;
  const ushort_t* Bb = Bh;
  if (MODE == 3) {
    int cls = blockIdx.z;
    py = cls >> 1;
    px = cls & 1;
    Bb = Bh + (size_t)cls * 262144;
  }
  const int srow = l & 15, chunk = l >> 4;
  const int tok1 = M0 + w * 32 + srow, tok2 = tok1 + 16;
  const int bR = N0 + w * 16 + srow;
  const int fr = l & 15, quad = l >> 4;
  const int m_off = (w & 1) * 64, n_off = (w >> 1) * 32;
  const int mset = (m_off >> 4), nset = (n_off >> 4);

  f32x4 acc[4][2];
#pragma unroll
  for (int i = 0; i < 4; ++i)
#pragma unroll
    for (int j = 0; j < 2; ++j) acc[i][j] = (f32x4){0.f, 0.f, 0.f, 0.f};

  const int n1 = tok1 >> 6, oy1 = (tok1 >> 3) & 7, ox1 = tok1 & 7;
  const int n2 = tok2 >> 6, oy2 = (tok2 >> 3) & 7, ox2 = tok2 & 7;
  const ushort_t* zp = zrow + chunk * 8;

  const int SUB = (STYLE == 1) ? 32 : 64;
  const int STEP = DB * SUB;
  for (int k0 = 0; k0 < K; k0 += STEP) {
#pragma unroll
    for (int d = 0; d < DB; ++d) {
      const int kk = k0 + d * SUB;
      const ushort_t *p1, *p2, *q1, *q2;
      if (MODE == 0) {
        size_t o1 = (size_t)tok1 * K + kk + chunk * 8;
        size_t o2 = (size_t)tok2 * K + kk + chunk * 8;
        p1 = Ah + o1;
        p2 = Ah + o2;
        q1 = (STYLE == 1) ? Al + o1 : Ah + o1 + 32;
        q2 = (STYLE == 1) ? Al + o2 : Ah + o2 + 32;
      } else {
        int tap = kk >> 8, kin = (kk & 255) + chunk * 8;
        int iy1, ix1, iy2, ix2;
        unsigned lim;
        if (MODE == 1) {
          int ky = tap >> 2, kx = tap & 3;
          iy1 = 2 * oy1 - 1 + ky; ix1 = 2 * ox1 - 1 + kx;
          iy2 = 2 * oy2 - 1 + ky; ix2 = 2 * ox2 - 1 + kx;
          lim = 16u;
        } else if (MODE == 2) {
          int ky = tap / 3, kx = tap - ky * 3;
          iy1 = oy1 - 1 + ky; ix1 = ox1 - 1 + kx;
          iy2 = oy2 - 1 + ky; ix2 = ox2 - 1 + kx;
          lim = 8u;
        } else {
          int s = tap >> 1, sx = tap & 1;
          iy1 = oy1 + s - py; ix1 = ox1 + sx - px;
          iy2 = oy2 + s - py; ix2 = ox2 + sx - px;
          lim = 8u;
        }
        bool v1 = ((unsigned)iy1 < lim && (unsigned)ix1 < lim);
        bool v2 = ((unsigned)iy2 < lim && (unsigned)ix2 < lim);
        size_t r1, r2;
        if (MODE == 1) {
          r1 = (size_t)(((n1 << 8) + (iy1 << 4) + ix1)) << 8;
          r2 = (size_t)(((n2 << 8) + (iy2 << 4) + ix2)) << 8;
        } else {
          r1 = (size_t)(((n1 << 6) + (iy1 << 3) + ix1)) << 8;
          r2 = (size_t)(((n2 << 6) + (iy2 << 3) + ix2)) << 8;
        }
        if (STYLE == 1) {
          p1 = v1 ? Ah + r1 + kin : zp;
          p2 = v2 ? Ah + r2 + kin : zp;
          q1 = v1 ? Al + r1 + kin : zp;
          q2 = v2 ? Al + r2 + kin : zp;
        } else {
          p1 = v1 ? Ah + r1 + kin : zp;
          p2 = v2 ? Ah + r2 + kin : zp;
          q1 = v1 ? Ah + r1 + kin + 32 : zp;
          q2 = v2 ? Ah + r2 + kin + 32 : zp;
        }
      }
      size_t bo = (size_t)bR * K + kk + chunk * 8;
      glds16(p1, A0[d] + w * 1024);
      glds16(p2, A0[d] + w * 1024 + 512);
      glds16(q1, A1s[d] + w * 1024);
      glds16(q2, A1s[d] + w * 1024 + 512);
      glds16(Bb + bo, B0[d] + w * 512);
      glds16((STYLE == 1) ? (Bl + bo) : (Bb + bo + 32), B1[d] + w * 512);
    }
    __syncthreads();
#pragma unroll
    for (int d = 0; d < DB; ++d) {
      short8v af0[4], af1[4], bf0[2], bf1[2];
#pragma unroll
      for (int mi = 0; mi < 4; ++mi) {
        af0[mi] = *(const short8v*)(A0[d] + (mset + mi) * 512 + quad * 128 + fr * 8);
        af1[mi] = *(const short8v*)(A1s[d] + (mset + mi) * 512 + quad * 128 + fr * 8);
      }
#pragma unroll
      for (int nj = 0; nj < 2; ++nj) {
        bf0[nj] = *(const short8v*)(B0[d] + (nset + nj) * 512 + quad * 128 + fr * 8);
        bf1[nj] = *(const short8v*)(B1[d] + (nset + nj) * 512 + quad * 128 + fr * 8);
      }
#pragma unroll
      for (int mi = 0; mi < 4; ++mi)
#pragma unroll
        for (int nj = 0; nj < 2; ++nj) {
          acc[mi][nj] =
              __builtin_amdgcn_mfma_f32_16x16x32_bf16(af0[mi], bf0[nj], acc[mi][nj], 0, 0, 0);
          if (STYLE == 1) {
            acc[mi][nj] =
                __builtin_amdgcn_mfma_f32_16x16x32_bf16(af1[mi], bf0[nj], acc[mi][nj], 0, 0, 0);
            acc[mi][nj] =
                __builtin_amdgcn_mfma_f32_16x16x32_bf16(af0[mi], bf1[nj], acc[mi][nj], 0, 0, 0);
          } else {
            acc[mi][nj] =
                __builtin_amdgcn_mfma_f32_16x16x32_bf16(af1[mi], bf1[nj], acc[mi][nj], 0, 0, 0);
          }
        }
    }
    __syncthreads();
  }

#pragma unroll
  for (int mi = 0; mi < 4; ++mi) {
    int mrow = m_off + mi * 16 + (l >> 4) * 4;
#pragma unroll
    for (int nj = 0; nj < 2; ++nj) {
      int col = N0 + n_off + nj * 16 + fr;
      float bv = bias[col];
#pragma unroll
      for (int i = 0; i < 4; ++i) {
        int m = M0 + mrow + i;
        float v = fmaxf(acc[mi][nj][i] + bv, 0.f);
        if (EPI == 1) {
          outf[(size_t)m * 256 + col] = v;
        } else if (EPI == 2) {
          size_t o = (size_t)m * 256 + col;
          outf[o] = res[o] + v;
        } else if (EPI == 3) {
          int nn = m >> 6, jj = (m >> 3) & 7, ii = m & 7;
          int oy = 2 * jj + 1 - py, ox = 2 * ii + 1 - px;
          outb[(size_t)((nn << 8) + oy * 16 + ox) * 256 + col] = f2bs(v);
        } else if (EPI == 4) {
          size_t o = (size_t)m * 256 + col;
          ushort_t h = f2bs(v);
          outb[o] = h;
          outb2[o] = f2bs(v - bs2f(h));
        } else {  // EPI 5
          size_t o = (size_t)m * 256 + col;
          float vv = res[o] + v;
          outf[o] = vv;
          outb[o] = f2bs(vv);
        }
      }
    }
  }
}

// ---------------- fused rmsnorm (coalesced rmsw via transposed LDS stage) ----------
template <int SPLIT>
__global__ void __launch_bounds__(256) k_rmsnorm(const float* __restrict__ in,
                                                 const float* __restrict__ rmsw,
                                                 ushort_t* __restrict__ NBh,
                                                 ushort_t* __restrict__ NBl) {
  extern __shared__ float wT[];  // 64*257 floats
  __shared__ float sd[256];
  __shared__ float s_scale;
  int n = blockIdx.x, t = threadIdx.x;
  const float* p = in + (size_t)n * 16384;
  for (int k = 0; k < 64; ++k) {
    int i = k * 256 + t;  // i = c*64 + j
    wT[(i & 63) * 257 + (i >> 6)] = rmsw[i];
  }
  float s = 0.f;
  const float4* p4 = (const float4*)p;
  for (int i = t; i < 4096; i += 256) {
    float4 v = p4[i];
    s += v.x * v.x + v.y * v.y + v.z * v.z + v.w * v.w;
  }
  sd[t] = s;
  __syncthreads();
  for (int k = 128; k > 0; k >>= 1) {
    if (t < k) sd[t] += sd[t + k];
    __syncthreads();
  }
  if (t == 0) s_scale = 1.0f / sqrtf(sd[0] / 16384.f + 1.1920929e-07f);
  __syncthreads();
  float scale = s_scale;
  ushort_t* oh = NBh + (size_t)n * 16384;
  ushort_t* ol = NBl + (size_t)n * 16384;
  for (int j = 0; j < 64; ++j) {
    int i = j * 256 + t;
    float v = p[i] * scale * wT[j * 257 + t];
    ushort_t h = f2bs(v);
    oh[i] = h;
    if (SPLIT) ol[i] = f2bs(v - bs2f(h));
  }
}

// ---------------- VQ ----------------
__global__ void __launch_bounds__(256) k_vq(const float* __restrict__ enc,
                                            const float* __restrict__ emb,
                                            const float* __restrict__ enorm,
                                            float* __restrict__ q, float* __restrict__ sse) {
  __shared__ float z[16][256];
  __shared__ float sc[512 * 16];
  __shared__ float bv[16][16];
  __shared__ int bi[16][16];
  __shared__ int idxs[16];
  int T0 = blockIdx.x * 16;
  int t = threadIdx.x;
  for (int j = 0; j < 16; ++j) z[j][t] = enc[(size_t)(T0 + j) * 256 + t];
  __syncthreads();
  float d0[16], d1[16];
#pragma unroll
  for (int j = 0; j < 16; ++j) { d0[j] = 0.f; d1[j] = 0.f; }
  const float4* e0 = (const float4*)(emb + (size_t)t * 256);
  const float4* e1 = (const float4*)(emb + (size_t)(t + 256) * 256);
  for (int c4 = 0; c4 < 64; ++c4) {
    float4 ea = e0[c4];
    float4 eb = e1[c4];
#pragma unroll
    for (int j = 0; j < 16; ++j) {
      float4 zv = *(const float4*)&z[j][c4 * 4];
      d0[j] += zv.x * ea.x + zv.y * ea.y + zv.z * ea.z + zv.w * ea.w;
      d1[j] += zv.x * eb.x + zv.y * eb.y + zv.z * eb.z + zv.w * eb.w;
    }
  }
  float en0 = enorm[t], en1 = enorm[t + 256];
#pragma unroll
  for (int j = 0; j < 16; ++j) {
    sc[t * 16 + j] = en0 - 2.f * d0[j];
    sc[(t + 256) * 16 + j] = en1 - 2.f * d1[j];
  }
  __syncthreads();
  {
    int j = t & 15, chunk = t >> 4;
    float best = 3.4e38f;
    int bidx = 0;
    int c0 = chunk * 32;
    for (int cc = 0; cc < 32; ++cc) {
      float v = sc[(c0 + cc) * 16 + j];
      if (v < best) { best = v; bidx = c0 + cc; }
    }
    bv[chunk][j] = best;
    bi[chunk][j] = bidx;
  }
  __syncthreads();
  if (t < 16) {
    float best = 3.4e38f;
    int bidx = 0;
    for (int c = 0; c < 16; ++c) {
      float v = bv[c][t];
      if (v < best) { best = v; bidx = bi[c][t]; }
    }
    idxs[t] = bidx;
  }
  __syncthreads();
  float sq = 0.f;
  for (int j = 0; j < 16; ++j) {
    float e = emb[(size_t)idxs[j] * 256 + t];
    q[(size_t)(T0 + j) * 256 + t] = e;
    float d = z[j][t] - e;
    sq += d * d;
  }
  __syncthreads();
  sc[t] = sq;
  __syncthreads();
  for (int k = 128; k > 0; k >>= 1) {
    if (t < k) sc[t] += sc[t + k];
    __syncthreads();
  }
  if (t == 0) atomicAdd(sse, sc[0]);
}

// ---------------- deconv2 + reconst loss ----------------
__global__ void __launch_bounds__(256) k_deconv2(const ushort_t* __restrict__ in,
                                                 const float* __restrict__ wT,
                                                 const float* __restrict__ bias,
                                                 const float* __restrict__ x,
                                                 float* __restrict__ dec,
                                                 float* __restrict__ sse) {
  __shared__ float patch[9216];
  __shared__ float red[768];
  int blk = blockIdx.x;
  int oy = blk & 31, n = blk >> 5;
  int t = threadIdx.x;
  int py = (oy + 1) & 1;
  int dy = (oy + 1 - py) >> 1;
  for (int it = 0; it < 36; ++it) {
    int s = it / 18, col = it - s * 18;
    int ix = col - 1, iy = dy - 1 + s;
    float v = 0.f;
    if ((unsigned)iy < 16u && (unsigned)ix < 16u)
      v = bs2f(in[(size_t)((n << 8) + iy * 16 + ix) * 256 + t]);
    patch[(t * 2 + s) * 18 + col] = v;
  }
  __syncthreads();
  int ox = t & 31, g = t >> 5;
  int px = (ox + 1) & 1;
  int dx = (ox + 1 - px) >> 1;
  int k00 = ((py + 2) * 4 + px + 2) * 3;
  int k01 = k00 - 6;
  int k10 = (py * 4 + px + 2) * 3;
  int k11 = k10 - 6;
  float a0 = 0.f, a1 = 0.f, a2 = 0.f;
  for (int ic = g * 32; ic < g * 32 + 32; ++ic) {
    const float* pp = patch + ic * 36;
    float v00 = pp[dx], v01 = pp[dx + 1], v10 = pp[18 + dx], v11 = pp[18 + dx + 1];
    const float* ww = wT + ic * 48;
    a0 += v00 * ww[k00 + 0] + v01 * ww[k01 + 0] + v10 * ww[k10 + 0] + v11 * ww[k11 + 0];
    a1 += v00 * ww[k00 + 1] + v01 * ww[k01 + 1] + v10 * ww[k10 + 1] + v11 * ww[k11 + 1];
    a2 += v00 * ww[k00 + 2] + v01 * ww[k01 + 2] + v10 * ww[k10 + 2] + v11 * ww[k11 + 2];
  }
  red[t * 3 + 0] = a0;
  red[t * 3 + 1] = a1;
  red[t * 3 + 2] = a2;
  __syncthreads();
  float sq = 0.f;
  if (t < 96) {
    int ox2 = t & 31, oc = t >> 5;
    float v = bias[oc];
#pragma unroll
    for (int g2 = 0; g2 < 8; ++g2) v += red[(g2 * 32 + ox2) * 3 + oc];
    int oi = ((n * 3 + oc) * 32 + oy) * 32 + ox2;
    dec[oi] = v;
    float d = v - x[oi];
    sq = d * d;
  }
  __syncthreads();
  red[t] = sq;
  __syncthreads();
  for (int k = 128; k > 0; k >>= 1) {
    if (t < k) red[t] += red[t + k];
    __syncthreads();
  }
  if (t == 0) atomicAdd(sse, red[0]);
}

__global__ void k_final(const float* __restrict__ acc, float* __restrict__ out) {
  if (threadIdx.x == 0 && blockIdx.x == 0) {
    float vq = acc[0] / 4194304.f;
    float rec = acc[1] / 786432.f;
    out[0] = rec + 2.f * vq;
    out[1] = rec;
    out[2] = vq;
    out[3] = vq;
  }
}

extern "C" void kernel_launch(void* const* d_in, const int* in_sizes, int n_in,
                              void* d_out, int out_size, void* d_ws, size_t ws_size,
                              hipStream_t stream) {
  (void)in_sizes; (void)n_in; (void)out_size; (void)ws_size;
  const float* x = (const float*)d_in[0];
  const float* ew1 = (const float*)d_in[1];
  const float* eb1 = (const float*)d_in[2];
  const float* ew2 = (const float*)d_in[3];
  const float* eb2 = (const float*)d_in[4];
  const float* rmsw = (const float*)d_in[5];
  const float* r3w = (const float*)d_in[6];
  const float* r3b = (const float*)d_in[7];
  const float* r1w = (const float*)d_in[8];
  const float* r1b = (const float*)d_in[9];
  const float* emb = (const float*)d_in[10];
  const float* dw1 = (const float*)d_in[11];
  const float* db1 = (const float*)d_in[12];
  const float* dw2 = (const float*)d_in[13];
  const float* db2 = (const float*)d_in[14];
  float* out = (float*)d_out;

  float* wsf = (float*)d_ws;
  float* P = wsf + OFF_P;
  float* enorm = wsf + OFF_ENORM;
  float* wTd2 = wsf + OFF_WTD2;
  float* acc = wsf + OFF_ACC;
  float* zrowf = wsf + OFF_ZROW;
  ushort_t* sb = (ushort_t*)(wsf + OFF_SHORT);
  ushort_t* H1H = sb + SO_H1H;
  ushort_t* H1L = sb + SO_H1L;
  float* Qf = (float*)(sb + SO_H1L);
  ushort_t* NBH = sb + SO_NBH;
  ushort_t* NBL = sb + SO_NBL;
  ushort_t* A1H = NBH;
  ushort_t* A1L = NBL;
  ushort_t* QB = NBL;
  ushort_t* W1H = sb + SO_W1H;
  ushort_t* W1L = sb + SO_W1L;
  ushort_t* W2H = sb + SO_W2H;
  ushort_t* W2L = sb + SO_W2L;
  ushort_t* W3EH = sb + SO_W3EH;
  ushort_t* W3EL = sb + SO_W3EL;
  ushort_t* W3D = sb + SO_W3D;
  ushort_t* W1REH = sb + SO_W1REH;
  ushort_t* W1REL = sb + SO_W1REL;
  ushort_t* W1RD = sb + SO_W1RD;
  ushort_t* WD1 = sb + SO_WD1;
  const ushort_t* zrow = (const ushort_t*)zrowf;
  const size_t RMS_LDS = 64 * 257 * sizeof(float);

  k_prep<<<34931, 256, 0, stream>>>(x, ew1, ew2, r3w, r1w, dw1, dw2, emb,
                                    W1H, W1L, W2H, W2L, W3EH, W3EL, W3D,
                                    W1REH, W1REL, W1RD, WD1, wTd2, enorm, acc,
                                    zrowf, A1H, A1L);

  // conv1 (split, K=64, SWZ: 512 m-tiles x 4 n-tiles -> 2048 blocks)
  k_gemm<0, 4, 1, 2, 1><<<dim3(2048), 256, 0, stream>>>(A1H, A1L, W1H, W1L, 64, eb1,
                                                        nullptr, nullptr, H1H, H1L, zrow);
  // conv2 (split, K=4096, SWZ)
  k_gemm<1, 1, 1, 2, 1><<<dim3(512), 256, 0, stream>>>(H1H, H1L, W2H, W2L, 4096, eb2,
                                                       nullptr, P, nullptr, nullptr, zrow);
  for (int rb = 0; rb < 2; ++rb) {
    k_rmsnorm<1><<<256, 256, RMS_LDS, stream>>>(P, rmsw + (size_t)(rb * 2 + 0) * 16384, NBH, NBL);
    k_gemm<2, 2, 1, 2, 1><<<dim3(512), 256, 0, stream>>>(
        NBH, NBL, W3EH + (size_t)rb * 589824, W3EL + (size_t)rb * 589824, 2304,
        r3b + rb * 256, P, Qf, nullptr, nullptr, zrow);
    k_rmsnorm<1><<<256, 256, RMS_LDS, stream>>>(Qf, rmsw + (size_t)(rb * 2 + 1) * 16384, NBH, NBL);
    k_gemm<0, 2, 1, 2, 1><<<dim3(512), 256, 0, stream>>>(
        NBH, NBL, W1REH + (size_t)rb * 65536, W1REL + (size_t)rb * 65536, 256,
        r1b + rb * 256, Qf, P, nullptr, nullptr, zrow);
  }

  k_vq<<<1024, 256, 0, stream>>>(P, emb, enorm, Qf, acc + 0);

  for (int rb = 2; rb < 4; ++rb) {
    k_rmsnorm<0><<<256, 256, RMS_LDS, stream>>>(Qf, rmsw + (size_t)(rb * 2 + 0) * 16384, NBH, NBL);
    k_gemm<2, 2, 0, 2, 1><<<dim3(512), 256, 0, stream>>>(
        NBH, nullptr, W3D + (size_t)(rb - 2) * 589824, nullptr, 2304,
        r3b + rb * 256, Qf, P, nullptr, nullptr, zrow);
    k_rmsnorm<0><<<256, 256, RMS_LDS, stream>>>(P, rmsw + (size_t)(rb * 2 + 1) * 16384, NBH, NBL);
    if (rb == 3) {
      k_gemm<0, 5, 0, 2, 1><<<dim3(512), 256, 0, stream>>>(
          NBH, nullptr, W1RD + (size_t)(rb - 2) * 65536, nullptr, 256,
          r1b + rb * 256, P, Qf, QB, nullptr, zrow);
    } else {
      k_gemm<0, 2, 0, 2, 1><<<dim3(512), 256, 0, stream>>>(
          NBH, nullptr, W1RD + (size_t)(rb - 2) * 65536, nullptr, 256,
          r1b + rb * 256, P, Qf, nullptr, nullptr, zrow);
    }
  }

  // deconv1 (plain, K=1024, 4 parity classes via z; unswizzled)
  k_gemm<3, 3, 0, 2, 0><<<dim3(128, 4, 4), 256, 0, stream>>>(
      QB, nullptr, WD1, nullptr, 1024, db1, nullptr, nullptr, H1H, nullptr, zrow);

  k_deconv2<<<8192, 256, 0, stream>>>(H1H, wTd2, db2, x, out + 4, acc + 1);
  k_final<<<1, 64, 0, stream>>>(acc, out);
}

// Round 12
// 1235.050 us; speedup vs baseline: 1.4371x; 1.0435x over previous
//
#include <hip/hip_runtime.h>
#include <hip/hip_bf16.h>

typedef unsigned short ushort_t;
typedef __attribute__((ext_vector_type(8))) short short8v;
typedef __attribute__((ext_vector_type(4))) float f32x4;

__device__ __forceinline__ ushort_t f2bs(float v) {
  union { __hip_bfloat16 h; ushort_t u; } cv;
  cv.h = __float2bfloat16(v);
  return cv.u;
}
__device__ __forceinline__ float bs2f(ushort_t u) {
  union { ushort_t u; __hip_bfloat16 h; } cv;
  cv.u = u;
  return __bfloat162float(cv.h);
}

__device__ __forceinline__ void glds16(const ushort_t* g, ushort_t* l) {
  __builtin_amdgcn_global_load_lds(
      (const __attribute__((address_space(1))) unsigned int*)(uintptr_t)g,
      (__attribute__((address_space(3))) unsigned int*)(unsigned int)(uintptr_t)l,
      16, 0, 0);
}

// ---------------- workspace layout ----------------
static constexpr size_t OFF_P = 0;
static constexpr size_t OFF_ENORM = 4194304;
static constexpr size_t OFF_WTD2 = 4194816;
static constexpr size_t OFF_ACC = 4207360;
static constexpr size_t OFF_ZROW = 4207368;
static constexpr size_t OFF_SHORT = 4207432;
static constexpr size_t SO_H1H = 0;
static constexpr size_t SO_H1L = 16777216;
static constexpr size_t SO_NBH = 33554432;
static constexpr size_t SO_NBL = 37748736;
static constexpr size_t SO_W1H = 41943040;
static constexpr size_t SO_W1L = 41959424;
static constexpr size_t SO_W2H = 41975808;
static constexpr size_t SO_W2L = 43024384;
static constexpr size_t SO_W3EH = 44072960;
static constexpr size_t SO_W3EL = 45252608;
static constexpr size_t SO_W3D = 46432256;
static constexpr size_t SO_W1REH = 47611904;
static constexpr size_t SO_W1REL = 47742976;
static constexpr size_t SO_W1RD = 47874048;
static constexpr size_t SO_WD1 = 48005120;

__device__ __forceinline__ void split_store(float v, ushort_t* hi, ushort_t* lo, size_t i) {
  ushort_t h = f2bs(v);
  hi[i] = h;
  lo[i] = f2bs(v - bs2f(h));
}

// ---------------- fused prep ----------------
__global__ void __launch_bounds__(256) k_prep(
    const float* __restrict__ x, const float* __restrict__ ew1,
    const float* __restrict__ ew2, const float* __restrict__ r3w,
    const float* __restrict__ r1w, const float* __restrict__ dw1,
    const float* __restrict__ dw2, const float* __restrict__ emb,
    ushort_t* __restrict__ W1H, ushort_t* __restrict__ W1L,
    ushort_t* __restrict__ W2H, ushort_t* __restrict__ W2L,
    ushort_t* __restrict__ W3EH, ushort_t* __restrict__ W3EL,
    ushort_t* __restrict__ W3D, ushort_t* __restrict__ W1REH,
    ushort_t* __restrict__ W1REL, ushort_t* __restrict__ W1RD,
    ushort_t* __restrict__ WD1, float* __restrict__ wTd2,
    float* __restrict__ enorm, float* __restrict__ acc, float* __restrict__ zrow,
    ushort_t* __restrict__ A1H, ushort_t* __restrict__ A1L) {
  int b = blockIdx.x, t = threadIdx.x;
  if (b < 64) {
    int i = b * 256 + t;
    int oc = i >> 6, k = i & 63;
    float v = 0.f;
    if (k < 48) {
      int tap = k / 3, ic = k - 3 * tap;
      v = ew1[(oc * 3 + ic) * 16 + tap];
    }
    split_store(v, W1H, W1L, i);
  } else if (b < 4160) {
    int i = (b - 64) * 256 + t;
    int oc = i >> 12, k = i & 4095;
    int tap = k >> 8, ic = k & 255;
    split_store(ew2[(oc * 256 + ic) * 16 + tap], W2H, W2L, i);
  } else if (b < 8768) {
    int i = (b - 4160) * 256 + t;
    int rb = i / 589824, r2 = i - rb * 589824;
    int oc = r2 / 2304, k = r2 - oc * 2304;
    int r9 = k >> 8, ic = k & 255;
    split_store(r3w[((rb * 256 + oc) * 256 + ic) * 9 + r9], W3EH, W3EL, i);
  } else if (b < 13376) {
    int i = (b - 8768) * 256 + t;
    int rb = i / 589824, r2 = i - rb * 589824;
    int oc = r2 / 2304, k = r2 - oc * 2304;
    int r9 = k >> 8, ic = k & 255;
    W3D[i] = f2bs(r3w[(((rb + 2) * 256 + oc) * 256 + ic) * 9 + r9]);
  } else if (b < 13888) {
    int i = (b - 13376) * 256 + t;
    split_store(r1w[i], W1REH, W1REL, i);
  } else if (b < 14400) {
    int i = (b - 13888) * 256 + t;
    W1RD[i] = f2bs(r1w[2 * 65536 + i]);
  } else if (b < 18496) {
    int i = (b - 14400) * 256 + t;
    int cls = i >> 18, r2 = i & 262143;
    int oc = r2 >> 10, k = r2 & 1023;
    int tap = k >> 8, ic = k & 255;
    int s = tap >> 1, sx = tap & 1;
    int py = cls >> 1, px = cls & 1;
    int ky = py + 2 - 2 * s, kx = px + 2 - 2 * sx;
    WD1[i] = f2bs(dw1[(ic * 256 + oc) * 16 + ky * 4 + kx]);
  } else if (b < 18544) {
    int i = (b - 18496) * 256 + t;
    if (i < 12288) {
      int kyx = i & 15;
      int r = i >> 4;
      int oc = r % 3;
      int ic = r / 3;
      wTd2[(ic * 16 + kyx) * 3 + oc] = dw2[i];
    }
  } else if (b < 18546) {
    int e = (b - 18544) * 256 + t;
    float s = 0.f;
    for (int c = 0; c < 256; ++c) {
      float v = emb[e * 256 + c];
      s += v * v;
    }
    enorm[e] = s;
  } else if (b == 18546) {
    if (t < 2) acc[t] = 0.f;
    if (t < 64) zrow[t] = 0.f;
  } else {
    int i = (b - 18547) * 256 + t;
    int t1 = i >> 6, k = i & 63;
    float v = 0.f;
    if (k < 48) {
      int tap = k / 3, ic = k - 3 * tap;
      int n = t1 >> 8, oy = (t1 >> 4) & 15, ox = t1 & 15;
      int ky = tap >> 2, kx = tap & 3;
      int iy = 2 * oy - 1 + ky, ix = 2 * ox - 1 + kx;
      if ((unsigned)iy < 32u && (unsigned)ix < 32u)
        v = x[((n * 3 + ic) * 32 + iy) * 32 + ix];
    }
    split_store(v, A1H, A1L, i);
  }
}

// ---------------- MFMA GEMM (r5 structure + XCD swizzle; DB=1) ----------
// BM=128, BN=64, 4 waves, wave tile 64x32. One sub-window per barrier (best
// measured config: r5 conv2=202us; DB=2 regressed to 222-225 via doubled
// in-flight staging inflating the barrier drain).
// SWZ=1: b -> m=(b>>5)*8+(b&7), n=(b>>3)&3 (A-sharers co-XCD; FETCH -40%).
// STYLE 1 (split, sub=32): AhBh+AlBh+AhBl = 24 MFMA/wave/window
// STYLE 0 (plain, sub=64): 16 MFMA/wave/window
template <int MODE, int EPI, int STYLE, int DB, int SWZ>
__global__ __launch_bounds__(256) void k_gemm(const ushort_t* __restrict__ Ah,
                                              const ushort_t* __restrict__ Al,
                                              const ushort_t* __restrict__ Bh,
                                              const ushort_t* __restrict__ Bl, int K,
                                              const float* __restrict__ bias,
                                              const float* __restrict__ res,
                                              float* __restrict__ outf,
                                              ushort_t* __restrict__ outb,
                                              ushort_t* __restrict__ outb2,
                                              const ushort_t* __restrict__ zrow) {
  __shared__ __align__(16) ushort_t A0[DB][128 * 32];
  __shared__ __align__(16) ushort_t A1s[DB][128 * 32];
  __shared__ __align__(16) ushort_t B0[DB][64 * 32];
  __shared__ __align__(16) ushort_t B1[DB][64 * 32];
  const int t = threadIdx.x;
  const int w = t >> 6, l = t & 63;
  int M0, N0;
  if (SWZ) {
    int b = blockIdx.x;
    M0 = (((b >> 5) << 3) | (b & 7)) * 128;
    N0 = ((b >> 3) & 3) * 64;
  } else {
    M0 = blockIdx.x * 128;
    N0 = blockIdx.y * 64;
  }
  int py = 0, px = 0;
  const ushort_t* Bb = Bh;
  if (MODE == 3) {
    int cls = blockIdx.z;
    py = cls >> 1;
    px = cls & 1;
    Bb = Bh + (size_t)cls * 262144;
  }
  const int srow = l & 15, chunk = l >> 4;
  const int tok1 = M0 + w * 32 + srow, tok2 = tok1 + 16;
  const int bR = N0 + w * 16 + srow;
  const int fr = l & 15, quad = l >> 4;
  const int m_off = (w & 1) * 64, n_off = (w >> 1) * 32;
  const int mset = (m_off >> 4), nset = (n_off >> 4);

  f32x4 acc[4][2];
#pragma unroll
  for (int i = 0; i < 4; ++i)
#pragma unroll
    for (int j = 0; j < 2; ++j) acc[i][j] = (f32x4){0.f, 0.f, 0.f, 0.f};

  const int n1 = tok1 >> 6, oy1 = (tok1 >> 3) & 7, ox1 = tok1 & 7;
  const int n2 = tok2 >> 6, oy2 = (tok2 >> 3) & 7, ox2 = tok2 & 7;
  const ushort_t* zp = zrow + chunk * 8;

  const int SUB = (STYLE == 1) ? 32 : 64;
  const int STEP = DB * SUB;
  for (int k0 = 0; k0 < K; k0 += STEP) {
#pragma unroll
    for (int d = 0; d < DB; ++d) {
      const int kk = k0 + d * SUB;
      const ushort_t *p1, *p2, *q1, *q2;
      if (MODE == 0) {
        size_t o1 = (size_t)tok1 * K + kk + chunk * 8;
        size_t o2 = (size_t)tok2 * K + kk + chunk * 8;
        p1 = Ah + o1;
        p2 = Ah + o2;
        q1 = (STYLE == 1) ? Al + o1 : Ah + o1 + 32;
        q2 = (STYLE == 1) ? Al + o2 : Ah + o2 + 32;
      } else {
        int tap = kk >> 8, kin = (kk & 255) + chunk * 8;
        int iy1, ix1, iy2, ix2;
        unsigned lim;
        if (MODE == 1) {
          int ky = tap >> 2, kx = tap & 3;
          iy1 = 2 * oy1 - 1 + ky; ix1 = 2 * ox1 - 1 + kx;
          iy2 = 2 * oy2 - 1 + ky; ix2 = 2 * ox2 - 1 + kx;
          lim = 16u;
        } else if (MODE == 2) {
          int ky = tap / 3, kx = tap - ky * 3;
          iy1 = oy1 - 1 + ky; ix1 = ox1 - 1 + kx;
          iy2 = oy2 - 1 + ky; ix2 = ox2 - 1 + kx;
          lim = 8u;
        } else {
          int s = tap >> 1, sx = tap & 1;
          iy1 = oy1 + s - py; ix1 = ox1 + sx - px;
          iy2 = oy2 + s - py; ix2 = ox2 + sx - px;
          lim = 8u;
        }
        bool v1 = ((unsigned)iy1 < lim && (unsigned)ix1 < lim);
        bool v2 = ((unsigned)iy2 < lim && (unsigned)ix2 < lim);
        size_t r1, r2;
        if (MODE == 1) {
          r1 = (size_t)(((n1 << 8) + (iy1 << 4) + ix1)) << 8;
          r2 = (size_t)(((n2 << 8) + (iy2 << 4) + ix2)) << 8;
        } else {
          r1 = (size_t)(((n1 << 6) + (iy1 << 3) + ix1)) << 8;
          r2 = (size_t)(((n2 << 6) + (iy2 << 3) + ix2)) << 8;
        }
        if (STYLE == 1) {
          p1 = v1 ? Ah + r1 + kin : zp;
          p2 = v2 ? Ah + r2 + kin : zp;
          q1 = v1 ? Al + r1 + kin : zp;
          q2 = v2 ? Al + r2 + kin : zp;
        } else {
          p1 = v1 ? Ah + r1 + kin : zp;
          p2 = v2 ? Ah + r2 + kin : zp;
          q1 = v1 ? Ah + r1 + kin + 32 : zp;
          q2 = v2 ? Ah + r2 + kin + 32 : zp;
        }
      }
      size_t bo = (size_t)bR * K + kk + chunk * 8;
      glds16(p1, A0[d] + w * 1024);
      glds16(p2, A0[d] + w * 1024 + 512);
      glds16(q1, A1s[d] + w * 1024);
      glds16(q2, A1s[d] + w * 1024 + 512);
      glds16(Bb + bo, B0[d] + w * 512);
      glds16((STYLE == 1) ? (Bl + bo) : (Bb + bo + 32), B1[d] + w * 512);
    }
    __syncthreads();
#pragma unroll
    for (int d = 0; d < DB; ++d) {
      short8v af0[4], af1[4], bf0[2], bf1[2];
#pragma unroll
      for (int mi = 0; mi < 4; ++mi) {
        af0[mi] = *(const short8v*)(A0[d] + (mset + mi) * 512 + quad * 128 + fr * 8);
        af1[mi] = *(const short8v*)(A1s[d] + (mset + mi) * 512 + quad * 128 + fr * 8);
      }
#pragma unroll
      for (int nj = 0; nj < 2; ++nj) {
        bf0[nj] = *(const short8v*)(B0[d] + (nset + nj) * 512 + quad * 128 + fr * 8);
        bf1[nj] = *(const short8v*)(B1[d] + (nset + nj) * 512 + quad * 128 + fr * 8);
      }
#pragma unroll
      for (int mi = 0; mi < 4; ++mi)
#pragma unroll
        for (int nj = 0; nj < 2; ++nj) {
          acc[mi][nj] =
              __builtin_amdgcn_mfma_f32_16x16x32_bf16(af0[mi], bf0[nj], acc[mi][nj], 0, 0, 0);
          if (STYLE == 1) {
            acc[mi][nj] =
                __builtin_amdgcn_mfma_f32_16x16x32_bf16(af1[mi], bf0[nj], acc[mi][nj], 0, 0, 0);
            acc[mi][nj] =
                __builtin_amdgcn_mfma_f32_16x16x32_bf16(af0[mi], bf1[nj], acc[mi][nj], 0, 0, 0);
          } else {
            acc[mi][nj] =
                __builtin_amdgcn_mfma_f32_16x16x32_bf16(af1[mi], bf1[nj], acc[mi][nj], 0, 0, 0);
          }
        }
    }
    __syncthreads();
  }

#pragma unroll
  for (int mi = 0; mi < 4; ++mi) {
    int mrow = m_off + mi * 16 + (l >> 4) * 4;
#pragma unroll
    for (int nj = 0; nj < 2; ++nj) {
      int col = N0 + n_off + nj * 16 + fr;
      float bv = bias[col];
#pragma unroll
      for (int i = 0; i < 4; ++i) {
        int m = M0 + mrow + i;
        float v = fmaxf(acc[mi][nj][i] + bv, 0.f);
        if (EPI == 1) {
          outf[(size_t)m * 256 + col] = v;
        } else if (EPI == 2) {
          size_t o = (size_t)m * 256 + col;
          outf[o] = res[o] + v;
        } else if (EPI == 3) {
          int nn = m >> 6, jj = (m >> 3) & 7, ii = m & 7;
          int oy = 2 * jj + 1 - py, ox = 2 * ii + 1 - px;
          outb[(size_t)((nn << 8) + oy * 16 + ox) * 256 + col] = f2bs(v);
        } else if (EPI == 4) {
          size_t o = (size_t)m * 256 + col;
          ushort_t h = f2bs(v);
          outb[o] = h;
          outb2[o] = f2bs(v - bs2f(h));
        } else {  // EPI 5
          size_t o = (size_t)m * 256 + col;
          float vv = res[o] + v;
          outf[o] = vv;
          outb[o] = f2bs(vv);
        }
      }
    }
  }
}

// ---------------- fused rmsnorm (coalesced rmsw via transposed LDS stage) ----------
template <int SPLIT>
__global__ void __launch_bounds__(256) k_rmsnorm(const float* __restrict__ in,
                                                 const float* __restrict__ rmsw,
                                                 ushort_t* __restrict__ NBh,
                                                 ushort_t* __restrict__ NBl) {
  extern __shared__ float wT[];  // 64*257 floats
  __shared__ float sd[256];
  __shared__ float s_scale;
  int n = blockIdx.x, t = threadIdx.x;
  const float* p = in + (size_t)n * 16384;
  for (int k = 0; k < 64; ++k) {
    int i = k * 256 + t;  // i = c*64 + j
    wT[(i & 63) * 257 + (i >> 6)] = rmsw[i];
  }
  float s = 0.f;
  const float4* p4 = (const float4*)p;
  for (int i = t; i < 4096; i += 256) {
    float4 v = p4[i];
    s += v.x * v.x + v.y * v.y + v.z * v.z + v.w * v.w;
  }
  sd[t] = s;
  __syncthreads();
  for (int k = 128; k > 0; k >>= 1) {
    if (t < k) sd[t] += sd[t + k];
    __syncthreads();
  }
  if (t == 0) s_scale = 1.0f / sqrtf(sd[0] / 16384.f + 1.1920929e-07f);
  __syncthreads();
  float scale = s_scale;
  ushort_t* oh = NBh + (size_t)n * 16384;
  ushort_t* ol = NBl + (size_t)n * 16384;
  for (int j = 0; j < 64; ++j) {
    int i = j * 256 + t;
    float v = p[i] * scale * wT[j * 257 + t];
    ushort_t h = f2bs(v);
    oh[i] = h;
    if (SPLIT) ol[i] = f2bs(v - bs2f(h));
  }
}

// ---------------- VQ ----------------
__global__ void __launch_bounds__(256) k_vq(const float* __restrict__ enc,
                                            const float* __restrict__ emb,
                                            const float* __restrict__ enorm,
                                            float* __restrict__ q, float* __restrict__ sse) {
  __shared__ float z[16][256];
  __shared__ float sc[512 * 16];
  __shared__ float bv[16][16];
  __shared__ int bi[16][16];
  __shared__ int idxs[16];
  int T0 = blockIdx.x * 16;
  int t = threadIdx.x;
  for (int j = 0; j < 16; ++j) z[j][t] = enc[(size_t)(T0 + j) * 256 + t];
  __syncthreads();
  float d0[16], d1[16];
#pragma unroll
  for (int j = 0; j < 16; ++j) { d0[j] = 0.f; d1[j] = 0.f; }
  const float4* e0 = (const float4*)(emb + (size_t)t * 256);
  const float4* e1 = (const float4*)(emb + (size_t)(t + 256) * 256);
  for (int c4 = 0; c4 < 64; ++c4) {
    float4 ea = e0[c4];
    float4 eb = e1[c4];
#pragma unroll
    for (int j = 0; j < 16; ++j) {
      float4 zv = *(const float4*)&z[j][c4 * 4];
      d0[j] += zv.x * ea.x + zv.y * ea.y + zv.z * ea.z + zv.w * ea.w;
      d1[j] += zv.x * eb.x + zv.y * eb.y + zv.z * eb.z + zv.w * eb.w;
    }
  }
  float en0 = enorm[t], en1 = enorm[t + 256];
#pragma unroll
  for (int j = 0; j < 16; ++j) {
    sc[t * 16 + j] = en0 - 2.f * d0[j];
    sc[(t + 256) * 16 + j] = en1 - 2.f * d1[j];
  }
  __syncthreads();
  {
    int j = t & 15, chunk = t >> 4;
    float best = 3.4e38f;
    int bidx = 0;
    int c0 = chunk * 32;
    for (int cc = 0; cc < 32; ++cc) {
      float v = sc[(c0 + cc) * 16 + j];
      if (v < best) { best = v; bidx = c0 + cc; }
    }
    bv[chunk][j] = best;
    bi[chunk][j] = bidx;
  }
  __syncthreads();
  if (t < 16) {
    float best = 3.4e38f;
    int bidx = 0;
    for (int c = 0; c < 16; ++c) {
      float v = bv[c][t];
      if (v < best) { best = v; bidx = bi[c][t]; }
    }
    idxs[t] = bidx;
  }
  __syncthreads();
  float sq = 0.f;
  for (int j = 0; j < 16; ++j) {
    float e = emb[(size_t)idxs[j] * 256 + t];
    q[(size_t)(T0 + j) * 256 + t] = e;
    float d = z[j][t] - e;
    sq += d * d;
  }
  __syncthreads();
  sc[t] = sq;
  __syncthreads();
  for (int k = 128; k > 0; k >>= 1) {
    if (t < k) sc[t] += sc[t + k];
    __syncthreads();
  }
  if (t == 0) atomicAdd(sse, sc[0]);
}

// ---------------- deconv2 + reconst loss ----------------
__global__ void __launch_bounds__(256) k_deconv2(const ushort_t* __restrict__ in,
                                                 const float* __restrict__ wT,
                                                 const float* __restrict__ bias,
                                                 const float* __restrict__ x,
                                                 float* __restrict__ dec,
                                                 float* __restrict__ sse) {
  __shared__ float patch[9216];
  __shared__ float red[768];
  int blk = blockIdx.x;
  int oy = blk & 31, n = blk >> 5;
  int t = threadIdx.x;
  int py = (oy + 1) & 1;
  int dy = (oy + 1 - py) >> 1;
  for (int it = 0; it < 36; ++it) {
    int s = it / 18, col = it - s * 18;
    int ix = col - 1, iy = dy - 1 + s;
    float v = 0.f;
    if ((unsigned)iy < 16u && (unsigned)ix < 16u)
      v = bs2f(in[(size_t)((n << 8) + iy * 16 + ix) * 256 + t]);
    patch[(t * 2 + s) * 18 + col] = v;
  }
  __syncthreads();
  int ox = t & 31, g = t >> 5;
  int px = (ox + 1) & 1;
  int dx = (ox + 1 - px) >> 1;
  int k00 = ((py + 2) * 4 + px + 2) * 3;
  int k01 = k00 - 6;
  int k10 = (py * 4 + px + 2) * 3;
  int k11 = k10 - 6;
  float a0 = 0.f, a1 = 0.f, a2 = 0.f;
  for (int ic = g * 32; ic < g * 32 + 32; ++ic) {
    const float* pp = patch + ic * 36;
    float v00 = pp[dx], v01 = pp[dx + 1], v10 = pp[18 + dx], v11 = pp[18 + dx + 1];
    const float* ww = wT + ic * 48;
    a0 += v00 * ww[k00 + 0] + v01 * ww[k01 + 0] + v10 * ww[k10 + 0] + v11 * ww[k11 + 0];
    a1 += v00 * ww[k00 + 1] + v01 * ww[k01 + 1] + v10 * ww[k10 + 1] + v11 * ww[k11 + 1];
    a2 += v00 * ww[k00 + 2] + v01 * ww[k01 + 2] + v10 * ww[k10 + 2] + v11 * ww[k11 + 2];
  }
  red[t * 3 + 0] = a0;
  red[t * 3 + 1] = a1;
  red[t * 3 + 2] = a2;
  __syncthreads();
  float sq = 0.f;
  if (t < 96) {
    int ox2 = t & 31, oc = t >> 5;
    float v = bias[oc];
#pragma unroll
    for (int g2 = 0; g2 < 8; ++g2) v += red[(g2 * 32 + ox2) * 3 + oc];
    int oi = ((n * 3 + oc) * 32 + oy) * 32 + ox2;
    dec[oi] = v;
    float d = v - x[oi];
    sq = d * d;
  }
  __syncthreads();
  red[t] = sq;
  __syncthreads();
  for (int k = 128; k > 0; k >>= 1) {
    if (t < k) red[t] += red[t + k];
    __syncthreads();
  }
  if (t == 0) atomicAdd(sse, red[0]);
}

__global__ void k_final(const float* __restrict__ acc, float* __restrict__ out) {
  if (threadIdx.x == 0 && blockIdx.x == 0) {
    float vq = acc[0] / 4194304.f;
    float rec = acc[1] / 786432.f;
    out[0] = rec + 2.f * vq;
    out[1] = rec;
    out[2] = vq;
    out[3] = vq;
  }
}

extern "C" void kernel_launch(void* const* d_in, const int* in_sizes, int n_in,
                              void* d_out, int out_size, void* d_ws, size_t ws_size,
                              hipStream_t stream) {
  (void)in_sizes; (void)n_in; (void)out_size; (void)ws_size;
  const float* x = (const float*)d_in[0];
  const float* ew1 = (const float*)d_in[1];
  const float* eb1 = (const float*)d_in[2];
  const float* ew2 = (const float*)d_in[3];
  const float* eb2 = (const float*)d_in[4];
  const float* rmsw = (const float*)d_in[5];
  const float* r3w = (const float*)d_in[6];
  const float* r3b = (const float*)d_in[7];
  const float* r1w = (const float*)d_in[8];
  const float* r1b = (const float*)d_in[9];
  const float* emb = (const float*)d_in[10];
  const float* dw1 = (const float*)d_in[11];
  const float* db1 = (const float*)d_in[12];
  const float* dw2 = (const float*)d_in[13];
  const float* db2 = (const float*)d_in[14];
  float* out = (float*)d_out;

  float* wsf = (float*)d_ws;
  float* P = wsf + OFF_P;
  float* enorm = wsf + OFF_ENORM;
  float* wTd2 = wsf + OFF_WTD2;
  float* acc = wsf + OFF_ACC;
  float* zrowf = wsf + OFF_ZROW;
  ushort_t* sb = (ushort_t*)(wsf + OFF_SHORT);
  ushort_t* H1H = sb + SO_H1H;
  ushort_t* H1L = sb + SO_H1L;
  float* Qf = (float*)(sb + SO_H1L);
  ushort_t* NBH = sb + SO_NBH;
  ushort_t* NBL = sb + SO_NBL;
  ushort_t* A1H = NBH;
  ushort_t* A1L = NBL;
  ushort_t* QB = NBL;
  ushort_t* W1H = sb + SO_W1H;
  ushort_t* W1L = sb + SO_W1L;
  ushort_t* W2H = sb + SO_W2H;
  ushort_t* W2L = sb + SO_W2L;
  ushort_t* W3EH = sb + SO_W3EH;
  ushort_t* W3EL = sb + SO_W3EL;
  ushort_t* W3D = sb + SO_W3D;
  ushort_t* W1REH = sb + SO_W1REH;
  ushort_t* W1REL = sb + SO_W1REL;
  ushort_t* W1RD = sb + SO_W1RD;
  ushort_t* WD1 = sb + SO_WD1;
  const ushort_t* zrow = (const ushort_t*)zrowf;
  const size_t RMS_LDS = 64 * 257 * sizeof(float);

  k_prep<<<34931, 256, 0, stream>>>(x, ew1, ew2, r3w, r1w, dw1, dw2, emb,
                                    W1H, W1L, W2H, W2L, W3EH, W3EL, W3D,
                                    W1REH, W1REL, W1RD, WD1, wTd2, enorm, acc,
                                    zrowf, A1H, A1L);

  // conv1 (split, K=64, SWZ)
  k_gemm<0, 4, 1, 1, 1><<<dim3(2048), 256, 0, stream>>>(A1H, A1L, W1H, W1L, 64, eb1,
                                                        nullptr, nullptr, H1H, H1L, zrow);
  // conv2 (split, K=4096, SWZ)
  k_gemm<1, 1, 1, 1, 1><<<dim3(512), 256, 0, stream>>>(H1H, H1L, W2H, W2L, 4096, eb2,
                                                       nullptr, P, nullptr, nullptr, zrow);
  for (int rb = 0; rb < 2; ++rb) {
    k_rmsnorm<1><<<256, 256, RMS_LDS, stream>>>(P, rmsw + (size_t)(rb * 2 + 0) * 16384, NBH, NBL);
    k_gemm<2, 2, 1, 1, 1><<<dim3(512), 256, 0, stream>>>(
        NBH, NBL, W3EH + (size_t)rb * 589824, W3EL + (size_t)rb * 589824, 2304,
        r3b + rb * 256, P, Qf, nullptr, nullptr, zrow);
    k_rmsnorm<1><<<256, 256, RMS_LDS, stream>>>(Qf, rmsw + (size_t)(rb * 2 + 1) * 16384, NBH, NBL);
    k_gemm<0, 2, 1, 1, 1><<<dim3(512), 256, 0, stream>>>(
        NBH, NBL, W1REH + (size_t)rb * 65536, W1REL + (size_t)rb * 65536, 256,
        r1b + rb * 256, Qf, P, nullptr, nullptr, zrow);
  }

  k_vq<<<1024, 256, 0, stream>>>(P, emb, enorm, Qf, acc + 0);

  for (int rb = 2; rb < 4; ++rb) {
    k_rmsnorm<0><<<256, 256, RMS_LDS, stream>>>(Qf, rmsw + (size_t)(rb * 2 + 0) * 16384, NBH, NBL);
    k_gemm<2, 2, 0, 1, 1><<<dim3(512), 256, 0, stream>>>(
        NBH, nullptr, W3D + (size_t)(rb - 2) * 589824, nullptr, 2304,
        r3b + rb * 256, Qf, P, nullptr, nullptr, zrow);
    k_rmsnorm<0><<<256, 256, RMS_LDS, stream>>>(P, rmsw + (size_t)(rb * 2 + 1) * 16384, NBH, NBL);
    if (rb == 3) {
      k_gemm<0, 5, 0, 1, 1><<<dim3(512), 256, 0, stream>>>(
          NBH, nullptr, W1RD + (size_t)(rb - 2) * 65536, nullptr, 256,
          r1b + rb * 256, P, Qf, QB, nullptr, zrow);
    } else {
      k_gemm<0, 2, 0, 1, 1><<<dim3(512), 256, 0, stream>>>(
          NBH, nullptr, W1RD + (size_t)(rb - 2) * 65536, nullptr, 256,
          r1b + rb * 256, P, Qf, nullptr, nullptr, zrow);
    }
  }

  // deconv1 (plain, K=1024, 4 parity classes via z; unswizzled)
  k_gemm<3, 3, 0, 1, 0><<<dim3(128, 4, 4), 256, 0, stream>>>(
      QB, nullptr, WD1, nullptr, 1024, db1, nullptr, nullptr, H1H, nullptr, zrow);

  k_deconv2<<<8192, 256, 0, stream>>>(H1H, wTd2, db2, x, out + 4, acc + 1);
  k_final<<<1, 64, 0, stream>>>(acc, out);
}

// Round 14
// 1159.812 us; speedup vs baseline: 1.5303x; 1.0649x over previous
//
#include <hip/hip_runtime.h>
#include <hip/hip_bf16.h>

typedef unsigned short ushort_t;
typedef __attribute__((ext_vector_type(8))) short short8v;
typedef __attribute__((ext_vector_type(4))) float f32x4;

__device__ __forceinline__ ushort_t f2bs(float v) {
  union { __hip_bfloat16 h; ushort_t u; } cv;
  cv.h = __float2bfloat16(v);
  return cv.u;
}
__device__ __forceinline__ float bs2f(ushort_t u) {
  union { ushort_t u; __hip_bfloat16 h; } cv;
  cv.u = u;
  return __bfloat162float(cv.h);
}

__device__ __forceinline__ void glds16(const ushort_t* g, ushort_t* l) {
  __builtin_amdgcn_global_load_lds(
      (const __attribute__((address_space(1))) unsigned int*)(uintptr_t)g,
      (__attribute__((address_space(3))) unsigned int*)(unsigned int)(uintptr_t)l,
      16, 0, 0);
}

// ---------------- workspace layout ----------------
static constexpr size_t OFF_P = 0;
static constexpr size_t OFF_ENORM = 4194304;
static constexpr size_t OFF_WTD2 = 4194816;
static constexpr size_t OFF_ACC = 4207360;
static constexpr size_t OFF_ZROW = 4207368;
static constexpr size_t OFF_EMBT = 4207432;   // fp32 embT [c=256][code=512]
static constexpr size_t OFF_SSQ = 4338504;    // 8 slots x 256 samples
static constexpr size_t OFF_SHORT = 4340552;  // 16B aligned (x4 bytes)
static constexpr size_t SO_H1H = 0;
static constexpr size_t SO_H1L = 16777216;
static constexpr size_t SO_NBH = 33554432;
static constexpr size_t SO_NBL = 37748736;
static constexpr size_t SO_W1H = 41943040;
static constexpr size_t SO_W1L = 41959424;
static constexpr size_t SO_W2H = 41975808;
static constexpr size_t SO_W2L = 43024384;
static constexpr size_t SO_W3EH = 44072960;
static constexpr size_t SO_W3EL = 45252608;
static constexpr size_t SO_W3D = 46432256;
static constexpr size_t SO_W1REH = 47611904;
static constexpr size_t SO_W1REL = 47742976;
static constexpr size_t SO_W1RD = 47874048;
static constexpr size_t SO_WD1 = 48005120;

__device__ __forceinline__ void split_store(float v, ushort_t* hi, ushort_t* lo, size_t i) {
  ushort_t h = f2bs(v);
  hi[i] = h;
  lo[i] = f2bs(v - bs2f(h));
}

// ---------------- fused prep ----------------
// ranges: [0,64) w1 | [64,4160) w2 | [4160,8768) w3e | [8768,13376) w3d
// [13376,13888) w1re | [13888,14400) w1rd | [14400,18496) wd1 | [18496,18544) dec2
// [18544,18546) enorm | 18546 zero | [18547,34931) conv1 im2col (16384 blocks EXACT)
// [34931,35443) embT
__global__ void __launch_bounds__(256) k_prep(
    const float* __restrict__ x, const float* __restrict__ ew1,
    const float* __restrict__ ew2, const float* __restrict__ r3w,
    const float* __restrict__ r1w, const float* __restrict__ dw1,
    const float* __restrict__ dw2, const float* __restrict__ emb,
    ushort_t* __restrict__ W1H, ushort_t* __restrict__ W1L,
    ushort_t* __restrict__ W2H, ushort_t* __restrict__ W2L,
    ushort_t* __restrict__ W3EH, ushort_t* __restrict__ W3EL,
    ushort_t* __restrict__ W3D, ushort_t* __restrict__ W1REH,
    ushort_t* __restrict__ W1REL, ushort_t* __restrict__ W1RD,
    ushort_t* __restrict__ WD1, float* __restrict__ wTd2,
    float* __restrict__ enorm, float* __restrict__ acc, float* __restrict__ zrow,
    float* __restrict__ embT, float* __restrict__ ssq,
    ushort_t* __restrict__ A1H, ushort_t* __restrict__ A1L) {
  int b = blockIdx.x, t = threadIdx.x;
  if (b < 64) {
    int i = b * 256 + t;
    int oc = i >> 6, k = i & 63;
    float v = 0.f;
    if (k < 48) {
      int tap = k / 3, ic = k - 3 * tap;
      v = ew1[(oc * 3 + ic) * 16 + tap];
    }
    split_store(v, W1H, W1L, i);
  } else if (b < 4160) {
    int i = (b - 64) * 256 + t;
    int oc = i >> 12, k = i & 4095;
    int tap = k >> 8, ic = k & 255;
    split_store(ew2[(oc * 256 + ic) * 16 + tap], W2H, W2L, i);
  } else if (b < 8768) {
    int i = (b - 4160) * 256 + t;
    int rb = i / 589824, r2 = i - rb * 589824;
    int oc = r2 / 2304, k = r2 - oc * 2304;
    int r9 = k >> 8, ic = k & 255;
    split_store(r3w[((rb * 256 + oc) * 256 + ic) * 9 + r9], W3EH, W3EL, i);
  } else if (b < 13376) {
    int i = (b - 8768) * 256 + t;
    int rb = i / 589824, r2 = i - rb * 589824;
    int oc = r2 / 2304, k = r2 - oc * 2304;
    int r9 = k >> 8, ic = k & 255;
    W3D[i] = f2bs(r3w[(((rb + 2) * 256 + oc) * 256 + ic) * 9 + r9]);
  } else if (b < 13888) {
    int i = (b - 13376) * 256 + t;
    split_store(r1w[i], W1REH, W1REL, i);
  } else if (b < 14400) {
    int i = (b - 13888) * 256 + t;
    W1RD[i] = f2bs(r1w[2 * 65536 + i]);
  } else if (b < 18496) {
    int i = (b - 14400) * 256 + t;
    int cls = i >> 18, r2 = i & 262143;
    int oc = r2 >> 10, k = r2 & 1023;
    int tap = k >> 8, ic = k & 255;
    int s = tap >> 1, sx = tap & 1;
    int py = cls >> 1, px = cls & 1;
    int ky = py + 2 - 2 * s, kx = px + 2 - 2 * sx;
    WD1[i] = f2bs(dw1[(ic * 256 + oc) * 16 + ky * 4 + kx]);
  } else if (b < 18544) {
    int i = (b - 18496) * 256 + t;
    if (i < 12288) {
      int kyx = i & 15;
      int r = i >> 4;
      int oc = r % 3;
      int ic = r / 3;
      wTd2[(ic * 16 + kyx) * 3 + oc] = dw2[i];
    }
  } else if (b < 18546) {
    int e = (b - 18544) * 256 + t;
    float s = 0.f;
    for (int c = 0; c < 256; ++c) {
      float v = emb[e * 256 + c];
      s += v * v;
    }
    enorm[e] = s;
  } else if (b == 18546) {
    if (t < 2) acc[t] = 0.f;
    if (t < 64) zrow[t] = 0.f;
    for (int k = t; k < 2048; k += 256) ssq[k] = 0.f;
  } else if (b < 34931) {  // conv1 im2col: exactly 16384 blocks
    int i = (b - 18547) * 256 + t;
    int t1 = i >> 6, k = i & 63;
    float v = 0.f;
    if (k < 48) {
      int tap = k / 3, ic = k - 3 * tap;
      int n = t1 >> 8, oy = (t1 >> 4) & 15, ox = t1 & 15;
      int ky = tap >> 2, kx = tap & 3;
      int iy = 2 * oy - 1 + ky, ix = 2 * ox - 1 + kx;
      if ((unsigned)iy < 32u && (unsigned)ix < 32u)
        v = x[((n * 3 + ic) * 32 + iy) * 32 + ix];
    }
    split_store(v, A1H, A1L, i);
  } else {  // [34931, 35443): embT [c][code] fp32
    int i = (b - 34931) * 256 + t;
    int code = i >> 8, c = i & 255;
    embT[c * 512 + code] = emb[i];
  }
}

// ---------------- MFMA GEMM (r12 structure + optional SSQ accumulation) ----------
// BM=128, BN=64, 4 waves, wave tile 64x32, DB=1, chunk-major LDS, SWZ locality.
// SSQ=1 (EPI 1/2 only): per-wave sum of stored^2 -> atomicAdd(ssqp[sample]);
// each wave spans exactly one sample (m_off=(w&1)*64, 64-token samples).
template <int MODE, int EPI, int STYLE, int DB, int SWZ, int SSQ>
__global__ __launch_bounds__(256) void k_gemm(const ushort_t* __restrict__ Ah,
                                              const ushort_t* __restrict__ Al,
                                              const ushort_t* __restrict__ Bh,
                                              const ushort_t* __restrict__ Bl, int K,
                                              const float* __restrict__ bias,
                                              const float* __restrict__ res,
                                              float* __restrict__ outf,
                                              ushort_t* __restrict__ outb,
                                              ushort_t* __restrict__ outb2,
                                              const ushort_t* __restrict__ zrow,
                                              float* __restrict__ ssqp) {
  __shared__ __align__(16) ushort_t A0[DB][128 * 32];
  __shared__ __align__(16) ushort_t A1s[DB][128 * 32];
  __shared__ __align__(16) ushort_t B0[DB][64 * 32];
  __shared__ __align__(16) ushort_t B1[DB][64 * 32];
  const int t = threadIdx.x;
  const int w = t >> 6, l = t & 63;
  int M0, N0;
  if (SWZ) {
    int b = blockIdx.x;
    M0 = (((b >> 5) << 3) | (b & 7)) * 128;
    N0 = ((b >> 3) & 3) * 64;
  } else {
    M0 = blockIdx.x * 128;
    N0 = blockIdx.y * 64;
  }
  int py = 0, px = 0;
  const ushort_t* Bb = Bh;
  if (MODE == 3) {
    int cls = blockIdx.z;
    py = cls >> 1;
    px = cls & 1;
    Bb = Bh + (size_t)cls * 262144;
  }
  const int srow = l & 15, chunk = l >> 4;
  const int tok1 = M0 + w * 32 + srow, tok2 = tok1 + 16;
  const int bR = N0 + w * 16 + srow;
  const int fr = l & 15, quad = l >> 4;
  const int m_off = (w & 1) * 64, n_off = (w >> 1) * 32;
  const int mset = (m_off >> 4), nset = (n_off >> 4);

  f32x4 acc[4][2];
#pragma unroll
  for (int i = 0; i < 4; ++i)
#pragma unroll
    for (int j = 0; j < 2; ++j) acc[i][j] = (f32x4){0.f, 0.f, 0.f, 0.f};

  const int n1 = tok1 >> 6, oy1 = (tok1 >> 3) & 7, ox1 = tok1 & 7;
  const int n2 = tok2 >> 6, oy2 = (tok2 >> 3) & 7, ox2 = tok2 & 7;
  const ushort_t* zp = zrow + chunk * 8;

  const int SUB = (STYLE == 1) ? 32 : 64;
  const int STEP = DB * SUB;
  for (int k0 = 0; k0 < K; k0 += STEP) {
#pragma unroll
    for (int d = 0; d < DB; ++d) {
      const int kk = k0 + d * SUB;
      const ushort_t *p1, *p2, *q1, *q2;
      if (MODE == 0) {
        size_t o1 = (size_t)tok1 * K + kk + chunk * 8;
        size_t o2 = (size_t)tok2 * K + kk + chunk * 8;
        p1 = Ah + o1;
        p2 = Ah + o2;
        q1 = (STYLE == 1) ? Al + o1 : Ah + o1 + 32;
        q2 = (STYLE == 1) ? Al + o2 : Ah + o2 + 32;
      } else {
        int tap = kk >> 8, kin = (kk & 255) + chunk * 8;
        int iy1, ix1, iy2, ix2;
        unsigned lim;
        if (MODE == 1) {
          int ky = tap >> 2, kx = tap & 3;
          iy1 = 2 * oy1 - 1 + ky; ix1 = 2 * ox1 - 1 + kx;
          iy2 = 2 * oy2 - 1 + ky; ix2 = 2 * ox2 - 1 + kx;
          lim = 16u;
        } else if (MODE == 2) {
          int ky = tap / 3, kx = tap - ky * 3;
          iy1 = oy1 - 1 + ky; ix1 = ox1 - 1 + kx;
          iy2 = oy2 - 1 + ky; ix2 = ox2 - 1 + kx;
          lim = 8u;
        } else {
          int s = tap >> 1, sx = tap & 1;
          iy1 = oy1 + s - py; ix1 = ox1 + sx - px;
          iy2 = oy2 + s - py; ix2 = ox2 + sx - px;
          lim = 8u;
        }
        bool v1 = ((unsigned)iy1 < lim && (unsigned)ix1 < lim);
        bool v2 = ((unsigned)iy2 < lim && (unsigned)ix2 < lim);
        size_t r1, r2;
        if (MODE == 1) {
          r1 = (size_t)(((n1 << 8) + (iy1 << 4) + ix1)) << 8;
          r2 = (size_t)(((n2 << 8) + (iy2 << 4) + ix2)) << 8;
        } else {
          r1 = (size_t)(((n1 << 6) + (iy1 << 3) + ix1)) << 8;
          r2 = (size_t)(((n2 << 6) + (iy2 << 3) + ix2)) << 8;
        }
        if (STYLE == 1) {
          p1 = v1 ? Ah + r1 + kin : zp;
          p2 = v2 ? Ah + r2 + kin : zp;
          q1 = v1 ? Al + r1 + kin : zp;
          q2 = v2 ? Al + r2 + kin : zp;
        } else {
          p1 = v1 ? Ah + r1 + kin : zp;
          p2 = v2 ? Ah + r2 + kin : zp;
          q1 = v1 ? Ah + r1 + kin + 32 : zp;
          q2 = v2 ? Ah + r2 + kin + 32 : zp;
        }
      }
      size_t bo = (size_t)bR * K + kk + chunk * 8;
      glds16(p1, A0[d] + w * 1024);
      glds16(p2, A0[d] + w * 1024 + 512);
      glds16(q1, A1s[d] + w * 1024);
      glds16(q2, A1s[d] + w * 1024 + 512);
      glds16(Bb + bo, B0[d] + w * 512);
      glds16((STYLE == 1) ? (Bl + bo) : (Bb + bo + 32), B1[d] + w * 512);
    }
    __syncthreads();
#pragma unroll
    for (int d = 0; d < DB; ++d) {
      short8v af0[4], af1[4], bf0[2], bf1[2];
#pragma unroll
      for (int mi = 0; mi < 4; ++mi) {
        af0[mi] = *(const short8v*)(A0[d] + (mset + mi) * 512 + quad * 128 + fr * 8);
        af1[mi] = *(const short8v*)(A1s[d] + (mset + mi) * 512 + quad * 128 + fr * 8);
      }
#pragma unroll
      for (int nj = 0; nj < 2; ++nj) {
        bf0[nj] = *(const short8v*)(B0[d] + (nset + nj) * 512 + quad * 128 + fr * 8);
        bf1[nj] = *(const short8v*)(B1[d] + (nset + nj) * 512 + quad * 128 + fr * 8);
      }
#pragma unroll
      for (int mi = 0; mi < 4; ++mi)
#pragma unroll
        for (int nj = 0; nj < 2; ++nj) {
          acc[mi][nj] =
              __builtin_amdgcn_mfma_f32_16x16x32_bf16(af0[mi], bf0[nj], acc[mi][nj], 0, 0, 0);
          if (STYLE == 1) {
            acc[mi][nj] =
                __builtin_amdgcn_mfma_f32_16x16x32_bf16(af1[mi], bf0[nj], acc[mi][nj], 0, 0, 0);
            acc[mi][nj] =
                __builtin_amdgcn_mfma_f32_16x16x32_bf16(af0[mi], bf1[nj], acc[mi][nj], 0, 0, 0);
          } else {
            acc[mi][nj] =
                __builtin_amdgcn_mfma_f32_16x16x32_bf16(af1[mi], bf1[nj], acc[mi][nj], 0, 0, 0);
          }
        }
    }
    __syncthreads();
  }

  float sq = 0.f;
#pragma unroll
  for (int mi = 0; mi < 4; ++mi) {
    int mrow = m_off + mi * 16 + (l >> 4) * 4;
#pragma unroll
    for (int nj = 0; nj < 2; ++nj) {
      int col = N0 + n_off + nj * 16 + fr;
      float bv = bias[col];
#pragma unroll
      for (int i = 0; i < 4; ++i) {
        int m = M0 + mrow + i;
        float v = fmaxf(acc[mi][nj][i] + bv, 0.f);
        if (EPI == 1) {
          outf[(size_t)m * 256 + col] = v;
          if (SSQ) sq += v * v;
        } else if (EPI == 2) {
          size_t o = (size_t)m * 256 + col;
          float vv = res[o] + v;
          outf[o] = vv;
          if (SSQ) sq += vv * vv;
        } else if (EPI == 3) {
          int nn = m >> 6, jj = (m >> 3) & 7, ii = m & 7;
          int oy = 2 * jj + 1 - py, ox = 2 * ii + 1 - px;
          outb[(size_t)((nn << 8) + oy * 16 + ox) * 256 + col] = f2bs(v);
        } else if (EPI == 4) {
          size_t o = (size_t)m * 256 + col;
          ushort_t h = f2bs(v);
          outb[o] = h;
          outb2[o] = f2bs(v - bs2f(h));
        } else {  // EPI 5
          size_t o = (size_t)m * 256 + col;
          float vv = res[o] + v;
          outf[o] = vv;
          outb[o] = f2bs(vv);
        }
      }
    }
  }
  if (SSQ) {
#pragma unroll
    for (int off = 32; off > 0; off >>= 1) sq += __shfl_down(sq, off, 64);
    if (l == 0) atomicAdd(&ssqp[(M0 >> 6) + (w & 1)], sq);
  }
}

// ---------------- rmsnorm normalize-only (scale from fused SSQ table) ----------
template <int SPLIT>
__global__ void __launch_bounds__(256) k_rmsnorm(const float* __restrict__ in,
                                                 const float* __restrict__ rmsw,
                                                 const float* __restrict__ ssq,
                                                 ushort_t* __restrict__ NBh,
                                                 ushort_t* __restrict__ NBl) {
  extern __shared__ float wT[];  // 64*257 floats
  int n = blockIdx.x, t = threadIdx.x;
  const float* p = in + (size_t)n * 16384;
  for (int k = 0; k < 64; ++k) {
    int i = k * 256 + t;  // i = c*64 + j
    wT[(i & 63) * 257 + (i >> 6)] = rmsw[i];
  }
  float scale = 1.0f / sqrtf(ssq[n] / 16384.f + 1.1920929e-07f);
  __syncthreads();
  ushort_t* oh = NBh + (size_t)n * 16384;
  ushort_t* ol = NBl + (size_t)n * 16384;
  for (int j = 0; j < 64; ++j) {
    int i = j * 256 + t;
    float v = p[i] * scale * wT[j * 257 + t];
    ushort_t h = f2bs(v);
    oh[i] = h;
    if (SPLIT) ol[i] = f2bs(v - bs2f(h));
  }
}

// ---------------- VQ (coalesced embT scores; fused q-SSQ) ----------------
__global__ void __launch_bounds__(256) k_vq(const float* __restrict__ enc,
                                            const float* __restrict__ embT,
                                            const float* __restrict__ emb,
                                            const float* __restrict__ enorm,
                                            float* __restrict__ q, float* __restrict__ sse,
                                            float* __restrict__ ssq4) {
  __shared__ float z[16][256];
  __shared__ float sc[512 * 16];
  __shared__ float bv[16][16];
  __shared__ int bi[16][16];
  __shared__ int idxs[16];
  int T0 = blockIdx.x * 16;
  int t = threadIdx.x;
  for (int j = 0; j < 16; ++j) z[j][t] = enc[(size_t)(T0 + j) * 256 + t];
  __syncthreads();
  float d0[16], d1[16];
#pragma unroll
  for (int j = 0; j < 16; ++j) { d0[j] = 0.f; d1[j] = 0.f; }
  for (int c4 = 0; c4 < 64; ++c4) {
    const float* eb = embT + (size_t)(c4 * 4) * 512 + t;  // [c][code] -> coalesced
    float e00 = eb[0], f00 = eb[256];
    float e01 = eb[512], f01 = eb[768];
    float e02 = eb[1024], f02 = eb[1280];
    float e03 = eb[1536], f03 = eb[1792];
#pragma unroll
    for (int j = 0; j < 16; ++j) {
      float4 zv = *(const float4*)&z[j][c4 * 4];
      d0[j] += zv.x * e00 + zv.y * e01 + zv.z * e02 + zv.w * e03;
      d1[j] += zv.x * f00 + zv.y * f01 + zv.z * f02 + zv.w * f03;
    }
  }
  float en0 = enorm[t], en1 = enorm[t + 256];
#pragma unroll
  for (int j = 0; j < 16; ++j) {
    sc[t * 16 + j] = en0 - 2.f * d0[j];
    sc[(t + 256) * 16 + j] = en1 - 2.f * d1[j];
  }
  __syncthreads();
  {
    int j = t & 15, chunk = t >> 4;
    float best = 3.4e38f;
    int bidx = 0;
    int c0 = chunk * 32;
    for (int cc = 0; cc < 32; ++cc) {
      float v = sc[(c0 + cc) * 16 + j];
      if (v < best) { best = v; bidx = c0 + cc; }
    }
    bv[chunk][j] = best;
    bi[chunk][j] = bidx;
  }
  __syncthreads();
  if (t < 16) {
    float best = 3.4e38f;
    int bidx = 0;
    for (int c = 0; c < 16; ++c) {
      float v = bv[c][t];
      if (v < best) { best = v; bidx = bi[c][t]; }
    }
    idxs[t] = bidx;
  }
  __syncthreads();
  float sq = 0.f, sqq = 0.f;
  for (int j = 0; j < 16; ++j) {
    float e = emb[(size_t)idxs[j] * 256 + t];
    q[(size_t)(T0 + j) * 256 + t] = e;
    float d = z[j][t] - e;
    sq += d * d;
    sqq += e * e;
  }
  __syncthreads();
  sc[t] = sq;
  __syncthreads();
  for (int k = 128; k > 0; k >>= 1) {
    if (t < k) sc[t] += sc[t + k];
    __syncthreads();
  }
  if (t == 0) atomicAdd(sse, sc[0]);
  __syncthreads();
  sc[t] = sqq;
  __syncthreads();
  for (int k = 128; k > 0; k >>= 1) {
    if (t < k) sc[t] += sc[t + k];
    __syncthreads();
  }
  if (t == 0) atomicAdd(&ssq4[blockIdx.x >> 2], sc[0]);
}

// ---------------- deconv2 + reconst loss ----------------
__global__ void __launch_bounds__(256) k_deconv2(const ushort_t* __restrict__ in,
                                                 const float* __restrict__ wT,
                                                 const float* __restrict__ bias,
                                                 const float* __restrict__ x,
                                                 float* __restrict__ dec,
                                                 float* __restrict__ sse) {
  __shared__ float patch[9216];
  __shared__ float red[768];
  int blk = blockIdx.x;
  int oy = blk & 31, n = blk >> 5;
  int t = threadIdx.x;
  int py = (oy + 1) & 1;
  int dy = (oy + 1 - py) >> 1;
  for (int it = 0; it < 36; ++it) {
    int s = it / 18, col = it - s * 18;
    int ix = col - 1, iy = dy - 1 + s;
    float v = 0.f;
    if ((unsigned)iy < 16u && (unsigned)ix < 16u)
      v = bs2f(in[(size_t)((n << 8) + iy * 16 + ix) * 256 + t]);
    patch[(t * 2 + s) * 18 + col] = v;
  }
  __syncthreads();
  int ox = t & 31, g = t >> 5;
  int px = (ox + 1) & 1;
  int dx = (ox + 1 - px) >> 1;
  int k00 = ((py + 2) * 4 + px + 2) * 3;
  int k01 = k00 - 6;
  int k10 = (py * 4 + px + 2) * 3;
  int k11 = k10 - 6;
  float a0 = 0.f, a1 = 0.f, a2 = 0.f;
  for (int ic = g * 32; ic < g * 32 + 32; ++ic) {
    const float* pp = patch + ic * 36;
    float v00 = pp[dx], v01 = pp[dx + 1], v10 = pp[18 + dx], v11 = pp[18 + dx + 1];
    const float* ww = wT + ic * 48;
    a0 += v00 * ww[k00 + 0] + v01 * ww[k01 + 0] + v10 * ww[k10 + 0] + v11 * ww[k11 + 0];
    a1 += v00 * ww[k00 + 1] + v01 * ww[k01 + 1] + v10 * ww[k10 + 1] + v11 * ww[k11 + 1];
    a2 += v00 * ww[k00 + 2] + v01 * ww[k01 + 2] + v10 * ww[k10 + 2] + v11 * ww[k11 + 2];
  }
  red[t * 3 + 0] = a0;
  red[t * 3 + 1] = a1;
  red[t * 3 + 2] = a2;
  __syncthreads();
  float sq = 0.f;
  if (t < 96) {
    int ox2 = t & 31, oc = t >> 5;
    float v = bias[oc];
#pragma unroll
    for (int g2 = 0; g2 < 8; ++g2) v += red[(g2 * 32 + ox2) * 3 + oc];
    int oi = ((n * 3 + oc) * 32 + oy) * 32 + ox2;
    dec[oi] = v;
    float d = v - x[oi];
    sq = d * d;
  }
  __syncthreads();
  red[t] = sq;
  __syncthreads();
  for (int k = 128; k > 0; k >>= 1) {
    if (t < k) red[t] += red[t + k];
    __syncthreads();
  }
  if (t == 0) atomicAdd(sse, red[0]);
}

__global__ void k_final(const float* __restrict__ acc, float* __restrict__ out) {
  if (threadIdx.x == 0 && blockIdx.x == 0) {
    float vq = acc[0] / 4194304.f;
    float rec = acc[1] / 786432.f;
    out[0] = rec + 2.f * vq;
    out[1] = rec;
    out[2] = vq;
    out[3] = vq;
  }
}

extern "C" void kernel_launch(void* const* d_in, const int* in_sizes, int n_in,
                              void* d_out, int out_size, void* d_ws, size_t ws_size,
                              hipStream_t stream) {
  (void)in_sizes; (void)n_in; (void)out_size; (void)ws_size;
  const float* x = (const float*)d_in[0];
  const float* ew1 = (const float*)d_in[1];
  const float* eb1 = (const float*)d_in[2];
  const float* ew2 = (const float*)d_in[3];
  const float* eb2 = (const float*)d_in[4];
  const float* rmsw = (const float*)d_in[5];
  const float* r3w = (const float*)d_in[6];
  const float* r3b = (const float*)d_in[7];
  const float* r1w = (const float*)d_in[8];
  const float* r1b = (const float*)d_in[9];
  const float* emb = (const float*)d_in[10];
  const float* dw1 = (const float*)d_in[11];
  const float* db1 = (const float*)d_in[12];
  const float* dw2 = (const float*)d_in[13];
  const float* db2 = (const float*)d_in[14];
  float* out = (float*)d_out;

  float* wsf = (float*)d_ws;
  float* P = wsf + OFF_P;
  float* enorm = wsf + OFF_ENORM;
  float* wTd2 = wsf + OFF_WTD2;
  float* acc = wsf + OFF_ACC;
  float* zrowf = wsf + OFF_ZROW;
  float* embT = wsf + OFF_EMBT;
  float* ssq = wsf + OFF_SSQ;
  ushort_t* sb = (ushort_t*)(wsf + OFF_SHORT);
  ushort_t* H1H = sb + SO_H1H;
  ushort_t* H1L = sb + SO_H1L;
  float* Qf = (float*)(sb + SO_H1L);
  ushort_t* NBH = sb + SO_NBH;
  ushort_t* NBL = sb + SO_NBL;
  ushort_t* A1H = NBH;
  ushort_t* A1L = NBL;
  ushort_t* QB = NBL;
  ushort_t* W1H = sb + SO_W1H;
  ushort_t* W1L = sb + SO_W1L;
  ushort_t* W2H = sb + SO_W2H;
  ushort_t* W2L = sb + SO_W2L;
  ushort_t* W3EH = sb + SO_W3EH;
  ushort_t* W3EL = sb + SO_W3EL;
  ushort_t* W3D = sb + SO_W3D;
  ushort_t* W1REH = sb + SO_W1REH;
  ushort_t* W1REL = sb + SO_W1REL;
  ushort_t* W1RD = sb + SO_W1RD;
  ushort_t* WD1 = sb + SO_WD1;
  const ushort_t* zrow = (const ushort_t*)zrowf;
  const size_t RMS_LDS = 64 * 257 * sizeof(float);

  k_prep<<<35443, 256, 0, stream>>>(x, ew1, ew2, r3w, r1w, dw1, dw2, emb,
                                    W1H, W1L, W2H, W2L, W3EH, W3EL, W3D,
                                    W1REH, W1REL, W1RD, WD1, wTd2, enorm, acc,
                                    zrowf, embT, ssq, A1H, A1L);

  // conv1 (split, K=64, SWZ)
  k_gemm<0, 4, 1, 1, 1, 0><<<dim3(2048), 256, 0, stream>>>(
      A1H, A1L, W1H, W1L, 64, eb1, nullptr, nullptr, H1H, H1L, zrow, nullptr);
  // conv2 (split, K=4096, SWZ) -> P, ssq slot 0
  k_gemm<1, 1, 1, 1, 1, 1><<<dim3(512), 256, 0, stream>>>(
      H1H, H1L, W2H, W2L, 4096, eb2, nullptr, P, nullptr, nullptr, zrow, ssq + 0);
  for (int rb = 0; rb < 2; ++rb) {
    k_rmsnorm<1><<<256, 256, RMS_LDS, stream>>>(
        P, rmsw + (size_t)(rb * 2 + 0) * 16384, ssq + (rb * 2 + 0) * 256, NBH, NBL);
    if (rb == 0)
      k_gemm<2, 2, 1, 1, 1, 1><<<dim3(512), 256, 0, stream>>>(
          NBH, NBL, W3EH, W3EL, 2304, r3b, P, Qf, nullptr, nullptr, zrow, ssq + 256);
    else
      k_gemm<2, 2, 1, 1, 1, 1><<<dim3(512), 256, 0, stream>>>(
          NBH, NBL, W3EH + 589824, W3EL + 589824, 2304, r3b + 256, P, Qf, nullptr,
          nullptr, zrow, ssq + 768);
    k_rmsnorm<1><<<256, 256, RMS_LDS, stream>>>(
        Qf, rmsw + (size_t)(rb * 2 + 1) * 16384, ssq + (rb * 2 + 1) * 256, NBH, NBL);
    if (rb == 0)
      k_gemm<0, 2, 1, 1, 1, 1><<<dim3(512), 256, 0, stream>>>(
          NBH, NBL, W1REH, W1REL, 256, r1b, Qf, P, nullptr, nullptr, zrow, ssq + 512);
    else
      k_gemm<0, 2, 1, 1, 1, 0><<<dim3(512), 256, 0, stream>>>(
          NBH, NBL, W1REH + 65536, W1REL + 65536, 256, r1b + 256, Qf, P, nullptr,
          nullptr, zrow, nullptr);
  }

  // VQ: P -> Qf (q), sse -> acc[0], q-ssq -> slot 4
  k_vq<<<1024, 256, 0, stream>>>(P, embT, emb, enorm, Qf, acc + 0, ssq + 1024);

  for (int rb = 2; rb < 4; ++rb) {
    k_rmsnorm<0><<<256, 256, RMS_LDS, stream>>>(
        Qf, rmsw + (size_t)(rb * 2 + 0) * 16384, ssq + (rb * 2 + 0) * 256, NBH, NBL);
    if (rb == 2)
      k_gemm<2, 2, 0, 1, 1, 1><<<dim3(512), 256, 0, stream>>>(
          NBH, nullptr, W3D, nullptr, 2304, r3b + 2 * 256, Qf, P, nullptr, nullptr,
          zrow, ssq + 1280);
    else
      k_gemm<2, 2, 0, 1, 1, 1><<<dim3(512), 256, 0, stream>>>(
          NBH, nullptr, W3D + 589824, nullptr, 2304, r3b + 3 * 256, Qf, P, nullptr,
          nullptr, zrow, ssq + 1792);
    k_rmsnorm<0><<<256, 256, RMS_LDS, stream>>>(
        P, rmsw + (size_t)(rb * 2 + 1) * 16384, ssq + (rb * 2 + 1) * 256, NBH, NBL);
    if (rb == 3) {
      k_gemm<0, 5, 0, 1, 1, 0><<<dim3(512), 256, 0, stream>>>(
          NBH, nullptr, W1RD + 65536, nullptr, 256, r1b + 3 * 256, P, Qf, QB, nullptr,
          zrow, nullptr);
    } else {
      k_gemm<0, 2, 0, 1, 1, 1><<<dim3(512), 256, 0, stream>>>(
          NBH, nullptr, W1RD, nullptr, 256, r1b + 2 * 256, P, Qf, nullptr, nullptr,
          zrow, ssq + 1536);
    }
  }

  // deconv1 (plain, K=1024, 4 parity classes via z; unswizzled)
  k_gemm<3, 3, 0, 1, 0, 0><<<dim3(128, 4, 4), 256, 0, stream>>>(
      QB, nullptr, WD1, nullptr, 1024, db1, nullptr, nullptr, H1H, nullptr, zrow, nullptr);

  k_deconv2<<<8192, 256, 0, stream>>>(H1H, wTd2, db2, x, out + 4, acc + 1);
  k_final<<<1, 64, 0, stream>>>(acc, out);
}